// Round 1
// baseline (4607.911 us; speedup 1.0000x reference)
//
#include <hip/hip_runtime.h>
#include <hip/hip_bf16.h>
#include <math.h>

constexpr int kBn    = 4;
constexpr int kText  = 64;
constexpr int kImg   = 256;
constexpr int kDim   = 1024;
constexpr int kHeads = 16;
constexpr int kHd    = 64;
constexpr int kNp    = 256;    // patches
constexpr int kTok   = 321;    // 64 text + 1 cls + 256 img
constexpr int kVocab = 50000;
constexpr int kTdim  = 256;
constexpr int kMlp   = 4096;
constexpr float kEps = 1e-5f;

// ---------------------------------------------------------------- generic GEMM
// C[m][n] = alpha * sum_k A[m][k] * B'[k][n]   (B' = B^T if BT: B stored [N][K])
// Epilogues: 0 none | 1 +bias[n] | 2 silu(+bias[n]) | 3 gelu | 4 +E[m][n] | 5 gated residual
struct GemmP {
  const float* A; const float* B; float* C; const float* E;
  int M, N, K, lda, ldb, ldc;
  long sA0, sA1, sB0, sB1, sC0, sC1, sE0, sE1;
  int innerB, ldE, rowsPB;
  float alpha;
};

template<int EPI, bool BT>
__global__ __launch_bounds__(256) void gemm_f32(GemmP p) {
  int bz = blockIdx.z;
  int b1 = bz % p.innerB, b0 = bz / p.innerB;
  const float* A = p.A + b0*p.sA0 + b1*p.sA1;
  const float* B = p.B + b0*p.sB0 + b1*p.sB1;
  float* C = p.C + b0*p.sC0 + b1*p.sC1;
  const float* E = p.E ? p.E + b0*p.sE0 + b1*p.sE1 : nullptr;

  __shared__ float As[16][65];
  __shared__ float Bs[16][65];
  int tid = threadIdx.x;
  int tx = tid & 15, ty = tid >> 4;
  int n0 = blockIdx.x * 64, m0 = blockIdx.y * 64;
  float acc[4][4] = {};
  for (int k0 = 0; k0 < p.K; k0 += 16) {
#pragma unroll
    for (int r = 0; r < 4; ++r) {
      int i = tid + 256*r;
      int kk = i & 15, mm = i >> 4;
      int m = m0 + mm, k = k0 + kk;
      As[kk][mm] = (m < p.M && k < p.K) ? A[(long)m*p.lda + k] : 0.f;
    }
    if (BT) {
#pragma unroll
      for (int r = 0; r < 4; ++r) {
        int i = tid + 256*r;
        int kk = i & 15, nn = i >> 4;
        int n = n0 + nn, k = k0 + kk;
        Bs[kk][nn] = (n < p.N && k < p.K) ? B[(long)n*p.ldb + k] : 0.f;
      }
    } else {
#pragma unroll
      for (int r = 0; r < 4; ++r) {
        int i = tid + 256*r;
        int nn = i & 63, kk = i >> 6;
        int n = n0 + nn, k = k0 + kk;
        Bs[kk][nn] = (n < p.N && k < p.K) ? B[(long)k*p.ldb + n] : 0.f;
      }
    }
    __syncthreads();
#pragma unroll
    for (int kk = 0; kk < 16; ++kk) {
      float a[4], b[4];
#pragma unroll
      for (int i = 0; i < 4; ++i) a[i] = As[kk][ty*4+i];
#pragma unroll
      for (int j = 0; j < 4; ++j) b[j] = Bs[kk][tx*4+j];
#pragma unroll
      for (int i = 0; i < 4; ++i)
#pragma unroll
        for (int j = 0; j < 4; ++j)
          acc[i][j] += a[i]*b[j];
    }
    __syncthreads();
  }
  for (int i = 0; i < 4; ++i) {
    int m = m0 + ty*4 + i;
    if (m >= p.M) continue;
    for (int j = 0; j < 4; ++j) {
      int n = n0 + tx*4 + j;
      if (n >= p.N) continue;
      float v = acc[i][j] * p.alpha;
      long co = (long)m*p.ldc + n;
      if (EPI == 1) v += E[n];
      else if (EPI == 2) { v += E[n]; v = v / (1.f + expf(-v)); }
      else if (EPI == 3) v = 0.5f*v*(1.f + erff(v*0.70710678118654752f));
      else if (EPI == 4) v += E[(long)m*p.ldE + n];
      else if (EPI == 5) v = C[co] + E[(long)(m / p.rowsPB)*p.ldE + n] * v;
      C[co] = v;
    }
  }
}

static GemmP mk(const float* A, const float* B, float* C,
                int M, int N, int K, int lda, int ldb, int ldc) {
  GemmP p; p.A = A; p.B = B; p.C = C; p.E = nullptr;
  p.M = M; p.N = N; p.K = K; p.lda = lda; p.ldb = ldb; p.ldc = ldc;
  p.sA0 = p.sA1 = p.sB0 = p.sB1 = p.sC0 = p.sC1 = p.sE0 = p.sE1 = 0;
  p.innerB = 1; p.ldE = 0; p.rowsPB = 1; p.alpha = 1.f;
  return p;
}

static void run_gemm(hipStream_t s, int epi, bool bt, const GemmP& p, int nbatch) {
  dim3 g((p.N + 63)/64, (p.M + 63)/64, nbatch), b(256, 1, 1);
  if (bt) {
    switch (epi) {
      case 0: gemm_f32<0,true><<<g,b,0,s>>>(p); break;
      case 1: gemm_f32<1,true><<<g,b,0,s>>>(p); break;
      case 2: gemm_f32<2,true><<<g,b,0,s>>>(p); break;
      case 3: gemm_f32<3,true><<<g,b,0,s>>>(p); break;
      case 4: gemm_f32<4,true><<<g,b,0,s>>>(p); break;
      case 5: gemm_f32<5,true><<<g,b,0,s>>>(p); break;
    }
  } else {
    switch (epi) {
      case 0: gemm_f32<0,false><<<g,b,0,s>>>(p); break;
      default: gemm_f32<0,false><<<g,b,0,s>>>(p); break;
    }
  }
}

// ---------------------------------------------------------------- small kernels
__global__ void embed_text_cls(const float* __restrict__ Wtok, const int* __restrict__ toks,
                               const float* __restrict__ pos_text, const float* __restrict__ cls_tok,
                               float* __restrict__ x) {
  int idx = blockIdx.x*256 + threadIdx.x;           // over B*65*DIM
  int d = idx % kDim;
  int t = (idx / kDim) % (kText + 1);
  int b = idx / (kDim * (kText + 1));
  float v;
  if (t < kText) {
    int tok = toks[b*kText + t];
    v = Wtok[(long)d*kVocab + tok] + pos_text[(long)t*kDim + d];
  } else {
    v = cls_tok[d];
  }
  x[((long)b*kTok + t)*kDim + d] = v;
}

__global__ void extract_patches(const float* __restrict__ img, float* __restrict__ pat) {
  int idx = blockIdx.x*256 + threadIdx.x;           // B*256*768
  int k = idx % 768;
  int p = (idx/768) % kNp;
  int b = idx/(768*kNp);
  int c = k >> 8, py = (k >> 4) & 15, px = k & 15;
  int hp = p >> 4, wp = p & 15;
  pat[idx] = img[(((long)(b*3 + c))*kImg + hp*16 + py)*kImg + wp*16 + px];
}

__global__ void time_freqs(const int* __restrict__ ts, float* __restrict__ temb) {
  int b = blockIdx.x, i = threadIdx.x;              // 128 threads
  float f = expf(-9.210340371976184f * (float)i / 128.f);  // exp(-ln(1e4)*i/half)
  float a = (float)ts[b] * f;
  temb[b*kTdim + i] = cosf(a);
  temb[b*kTdim + 128 + i] = sinf(a);
}

__global__ void silu_kernel(const float* __restrict__ in, float* __restrict__ outp, int n) {
  int i = blockIdx.x*256 + threadIdx.x;
  if (i < n) { float x = in[i]; outp[i] = x / (1.f + expf(-x)); }
}

__device__ __forceinline__ float block_sum(float v) {
  __shared__ float sh[4];
  for (int off = 32; off; off >>= 1) v += __shfl_down(v, off);
  if ((threadIdx.x & 63) == 0) sh[threadIdx.x >> 6] = v;
  __syncthreads();
  float s = sh[0] + sh[1] + sh[2] + sh[3];
  __syncthreads();
  return s;
}

// xn = LN(x; g,b) * (1 + mod[b][scOff+d]) + mod[b][shOff+d]
__global__ __launch_bounds__(256) void ln_mod_kernel(
    const float* __restrict__ x, const float* __restrict__ g, const float* __restrict__ be,
    const float* __restrict__ mod, int shOff, int scOff, float* __restrict__ outp) {
  int row = blockIdx.x;                 // b*321 + t
  int b = row / kTok;
  const float* xr = x + (long)row*kDim;
  float s = 0.f, s2 = 0.f;
  for (int i = threadIdx.x; i < kDim; i += 256) { float v = xr[i]; s += v; s2 += v*v; }
  s = block_sum(s); s2 = block_sum(s2);
  float m = s / kDim;
  float inv = rsqrtf(s2 / kDim - m*m + kEps);
  const float* mb = mod + (long)b*(6*kDim);
  for (int i = threadIdx.x; i < kDim; i += 256) {
    float xn = (xr[i] - m)*inv*g[i] + be[i];
    outp[(long)row*kDim + i] = xn*(1.f + mb[scOff + i]) + mb[shOff + i];
  }
}

__global__ __launch_bounds__(256) void final_ln_kernel(
    const float* __restrict__ x, const float* __restrict__ g, const float* __restrict__ be,
    float* __restrict__ yn) {
  int row = blockIdx.x;                 // b*256 + p
  int b = row / kNp, p = row % kNp;
  const float* xr = x + ((long)(b*kTok + kText + 1 + p))*kDim;
  float s = 0.f, s2 = 0.f;
  for (int i = threadIdx.x; i < kDim; i += 256) { float v = xr[i]; s += v; s2 += v*v; }
  s = block_sum(s); s2 = block_sum(s2);
  float m = s / kDim;
  float inv = rsqrtf(s2 / kDim - m*m + kEps);
  for (int i = threadIdx.x; i < kDim; i += 256)
    yn[(long)row*kDim + i] = (xr[i] - m)*inv*g[i] + be[i];
}

// RoPE in-place on q and k. Blocks of 256 cover exactly 4 whole heads, so the
// read-before-barrier / write-after-barrier pattern is race-free.
__global__ __launch_bounds__(256) void rope_kernel(float* __restrict__ q, float* __restrict__ k) {
  int idx = blockIdx.x*256 + threadIdx.x;          // B*321*1024, divisible by 256
  int d = idx & (kDim - 1);
  int n = (idx / kDim) % kTok;
  int hd = d & 63;
  int j = hd & 31;
  float inv = expf(-9.210340371976184f * (float)j / 32.f);   // 1/10000^(j/32)
  float ang = (float)n * inv;
  float c = cosf(ang), s = sinf(ang);
  int base = idx - hd;
  float qv = q[idx], kv = k[idx];
  float qr, kr;
  if (hd < 32) { qr = -q[base + 2*hd + 1]; kr = -k[base + 2*hd + 1]; }
  else         { qr =  q[base + 2*(hd - 32)]; kr = k[base + 2*(hd - 32)]; }
  __syncthreads();
  q[idx] = qv*c + qr*s;
  k[idx] = kv*c + kr*s;
}

__global__ void softmax_rows(float* __restrict__ sc, int rowLen) {
  long row = blockIdx.x;
  float* r = sc + row*rowLen;
  int t = threadIdx.x;                              // 64 threads = 1 wave
  float mx = -1e30f;
  for (int i = t; i < rowLen; i += 64) mx = fmaxf(mx, r[i]);
  for (int off = 32; off; off >>= 1) mx = fmaxf(mx, __shfl_xor(mx, off));
  float sum = 0.f;
  for (int i = t; i < rowLen; i += 64) { float e = expf(r[i] - mx); r[i] = e; sum += e; }
  for (int off = 32; off; off >>= 1) sum += __shfl_xor(sum, off);
  float invs = 1.f / sum;
  for (int i = t; i < rowLen; i += 64) r[i] *= invs;
}

__global__ void unpatchify(const float* __restrict__ op, float* __restrict__ outp) {
  int idx = blockIdx.x*256 + threadIdx.x;           // B*3*256*256
  int w = idx & 255;
  int h = (idx >> 8) & 255;
  int c = (idx >> 16) % 3;
  int b = idx / (3 * kImg * kImg);
  int hp = h >> 4, py = h & 15, wp = w >> 4, px = w & 15;
  outp[idx] = op[((long)(b*kNp + hp*16 + wp))*768 + c*256 + py*16 + px];
}

// ---------------------------------------------------------------- launch
extern "C" void kernel_launch(void* const* d_in, const int* in_sizes, int n_in,
                              void* d_out, int out_size, void* d_ws, size_t ws_size,
                              hipStream_t stream) {
  (void)in_sizes; (void)n_in; (void)out_size; (void)ws_size;
  const float* noisy    = (const float*)d_in[0];
  const int*   toks     = (const int*)d_in[1];
  const int*   tsteps   = (const int*)d_in[2];
  const float* W_tok    = (const float*)d_in[3];
  const float* pos_text = (const float*)d_in[4];
  const float* W_patch  = (const float*)d_in[5];
  const float* pos_img  = (const float*)d_in[6];
  const float* cls_tok  = (const float*)d_in[7];
  const float* W_t1     = (const float*)d_in[8];
  const float* b_t1     = (const float*)d_in[9];
  const float* W_t2     = (const float*)d_in[10];
  const float* b_t2     = (const float*)d_in[11];
  const float* ln1_g    = (const float*)d_in[12];
  const float* ln1_b    = (const float*)d_in[13];
  const float* Wq       = (const float*)d_in[14];
  const float* Wk       = (const float*)d_in[15];
  const float* Wv       = (const float*)d_in[16];
  const float* Wo       = (const float*)d_in[17];
  const float* ln2_g    = (const float*)d_in[18];
  const float* ln2_b    = (const float*)d_in[19];
  const float* Wm1      = (const float*)d_in[20];
  const float* Wm2      = (const float*)d_in[21];
  const float* Wada     = (const float*)d_in[22];
  const float* b_ada    = (const float*)d_in[23];
  const float* fn_g     = (const float*)d_in[24];
  const float* fn_b     = (const float*)d_in[25];
  const float* W_final  = (const float*)d_in[26];
  const float* b_final  = (const float*)d_in[27];
  float* out = (float*)d_out;

  float* ws = (float*)d_ws;
  const long seqSz = (long)kBn * kTok * kDim;        // 1,314,816
  float* x    = ws;              ws += seqSz;
  float* xn   = ws;              ws += seqSz;
  float* q    = ws;              ws += seqSz;
  float* k    = ws;              ws += seqSz;
  float* v    = ws;              ws += seqSz;
  float* o    = ws;              ws += seqSz;
  float* sc   = ws;              ws += (long)kBn*kHeads*kTok*kTok;  // also MLP hidden (bigger)
  float* pat  = ws;              ws += (long)kBn*kNp*768;
  float* temb = ws;              ws += kBn*kTdim;
  float* t1   = ws;              ws += kBn*kDim;
  float* temb2= ws;              ws += kBn*kDim;
  float* st   = ws;              ws += kBn*kDim;
  float* mod  = ws;              ws += 2L*kBn*6*kDim;
  float* yn   = ws;              ws += (long)kBn*kNp*kDim;
  float* outp = ws;              ws += (long)kBn*kNp*768;

  // --- embeddings
  embed_text_cls<<<(kBn*(kText+1)*kDim)/256, 256, 0, stream>>>(W_tok, toks, pos_text, cls_tok, x);
  extract_patches<<<(kBn*kNp*768)/256, 256, 0, stream>>>(noisy, pat);
  {
    GemmP p = mk(pat, W_patch, x + (kText+1)*kDim, kNp, kDim, 768, 768, 768, kDim);
    p.sA0 = (long)kNp*768; p.sC0 = (long)kTok*kDim;
    p.E = pos_img; p.ldE = kDim;
    run_gemm(stream, 4, true, p, kBn);
  }
  // --- time embedding
  time_freqs<<<kBn, 128, 0, stream>>>(tsteps, temb);
  { GemmP p = mk(temb, W_t1, t1, kBn, kDim, kTdim, kTdim, kTdim, kDim); p.E = b_t1;
    run_gemm(stream, 2, true, p, 1); }
  { GemmP p = mk(t1, W_t2, temb2, kBn, kDim, kDim, kDim, kDim, kDim); p.E = b_t2;
    run_gemm(stream, 1, true, p, 1); }
  silu_kernel<<<(kBn*kDim + 255)/256, 256, 0, stream>>>(temb2, st, kBn*kDim);

  for (int l = 0; l < 2; ++l) {
    const float* Wq_l = Wq + (long)l*kDim*kDim;
    const float* Wk_l = Wk + (long)l*kDim*kDim;
    const float* Wv_l = Wv + (long)l*kDim*kDim;
    const float* Wo_l = Wo + (long)l*kDim*kDim;
    const float* Wm1_l = Wm1 + (long)l*kMlp*kDim;
    const float* Wm2_l = Wm2 + (long)l*kDim*kMlp;
    float* mod_l = mod + (long)l*kBn*6*kDim;

    { GemmP p = mk(st, Wada + (long)l*6*kDim*kDim, mod_l, kBn, 6*kDim, kDim, kDim, kDim, 6*kDim);
      p.E = b_ada + (long)l*6*kDim;
      run_gemm(stream, 1, true, p, 1); }

    ln_mod_kernel<<<kBn*kTok, 256, 0, stream>>>(x, ln1_g + l*kDim, ln1_b + l*kDim,
                                                mod_l, 0, kDim, xn);
    { GemmP p = mk(xn, Wq_l, q, kBn*kTok, kDim, kDim, kDim, kDim, kDim); run_gemm(stream, 0, true, p, 1); }
    { GemmP p = mk(xn, Wk_l, k, kBn*kTok, kDim, kDim, kDim, kDim, kDim); run_gemm(stream, 0, true, p, 1); }
    { GemmP p = mk(xn, Wv_l, v, kBn*kTok, kDim, kDim, kDim, kDim, kDim); run_gemm(stream, 0, true, p, 1); }
    rope_kernel<<<(int)(seqSz/256), 256, 0, stream>>>(q, k);

    { // scores = 0.125 * q @ k^T per (b,h)
      GemmP p = mk(q, k, sc, kTok, kTok, kHd, kDim, kDim, kTok);
      p.sA0 = (long)kTok*kDim; p.sA1 = kHd;
      p.sB0 = (long)kTok*kDim; p.sB1 = kHd;
      p.sC0 = (long)kHeads*kTok*kTok; p.sC1 = (long)kTok*kTok;
      p.innerB = kHeads; p.alpha = 0.125f;
      run_gemm(stream, 0, true, p, kBn*kHeads);
    }
    softmax_rows<<<kBn*kHeads*kTok, 64, 0, stream>>>(sc, kTok);
    { // o = P @ V per (b,h)   (B not transposed)
      GemmP p = mk(sc, v, o, kTok, kHd, kTok, kTok, kDim, kDim);
      p.sA0 = (long)kHeads*kTok*kTok; p.sA1 = (long)kTok*kTok;
      p.sB0 = (long)kTok*kDim; p.sB1 = kHd;
      p.sC0 = (long)kTok*kDim; p.sC1 = kHd;
      p.innerB = kHeads;
      run_gemm(stream, 0, false, p, kBn*kHeads);
    }
    { // x += g_msa * (o @ Wo^T)
      GemmP p = mk(o, Wo_l, x, kBn*kTok, kDim, kDim, kDim, kDim, kDim);
      p.E = mod_l + 2*kDim; p.ldE = 6*kDim; p.rowsPB = kTok;
      run_gemm(stream, 5, true, p, 1);
    }
    ln_mod_kernel<<<kBn*kTok, 256, 0, stream>>>(x, ln2_g + l*kDim, ln2_b + l*kDim,
                                                mod_l, 3*kDim, 4*kDim, xn);
    { GemmP p = mk(xn, Wm1_l, sc, kBn*kTok, kMlp, kDim, kDim, kDim, kMlp);
      run_gemm(stream, 3, true, p, 1); }
    { GemmP p = mk(sc, Wm2_l, x, kBn*kTok, kDim, kMlp, kMlp, kMlp, kDim);
      p.E = mod_l + 5*kDim; p.ldE = 6*kDim; p.rowsPB = kTok;
      run_gemm(stream, 5, true, p, 1); }
  }

  final_ln_kernel<<<kBn*kNp, 256, 0, stream>>>(x, fn_g, fn_b, yn);
  { GemmP p = mk(yn, W_final, outp, kBn*kNp, 768, kDim, kDim, kDim, 768);
    p.E = b_final;
    run_gemm(stream, 1, true, p, 1); }
  unpatchify<<<(kBn*3*kImg*kImg)/256, 256, 0, stream>>>(outp, out);
}

// Round 2
// 1681.997 us; speedup vs baseline: 2.7395x; 2.7395x over previous
//
#include <hip/hip_runtime.h>
#include <hip/hip_bf16.h>
#include <math.h>

constexpr int kBn    = 4;
constexpr int kText  = 64;
constexpr int kImg   = 256;
constexpr int kDim   = 1024;
constexpr int kHeads = 16;
constexpr int kHd    = 64;
constexpr int kNp    = 256;    // patches
constexpr int kTok   = 321;    // 64 text + 1 cls + 256 img
constexpr int kVocab = 50000;
constexpr int kTdim  = 256;
constexpr int kMlp   = 4096;
constexpr int kScLd  = 328;    // score row stride (321 padded to mult of 8 for float4 staging)
constexpr float kEps = 1e-5f;

typedef __attribute__((ext_vector_type(8))) short short8;
typedef __attribute__((ext_vector_type(4))) float f32x4;

// RNE float -> bf16 bits (avoids hip_bf16 API/version differences)
__device__ __forceinline__ short f2bf(float x) {
  unsigned u = __builtin_bit_cast(unsigned, x);
  unsigned r = (u + 0x7FFFu + ((u >> 16) & 1u)) >> 16;
  return (short)r;
}

// =================================================================== MFMA GEMM
// C[m][n] = alpha * sum_k A[m][k] * Bt[n][k]    (both operands fp32 in memory,
// converted to bf16 during LDS staging; MFMA 16x16x32 bf16; fp32 accumulate)
// EPI: 0 none | 1 +bias[n] | 3 gelu | 4 +E[m][n] | 5 gated residual
// TRANS: write C[n][m] (used for V^T)
struct GemmM {
  const float* A; const float* B; float* C; const float* E;
  int M, N, K, lda, ldb, ldc;
  long sA0, sA1, sB0, sB1, sC0, sC1;
  int innerB, ldE, rowsPB;
  float alpha;
};

template<int EPI, bool TRANS>
__global__ __launch_bounds__(256) void gemm_mfma(GemmM p) {
  int bz = blockIdx.z;
  int b1 = bz % p.innerB, b0 = bz / p.innerB;
  const float* A = p.A + b0*p.sA0 + b1*p.sA1;
  const float* B = p.B + b0*p.sB0 + b1*p.sB1;
  float* C = p.C + b0*p.sC0 + b1*p.sC1;
  const float* E = p.E;

  __shared__ short As[64*72];   // rows = m (64), cols = k (64) + pad 8
  __shared__ short Bs[64*72];   // rows = n (64), cols = k (64) + pad 8

  int tid  = threadIdx.x;
  int lane = tid & 63, widx = tid >> 6;
  int quad = lane >> 4, ln = lane & 15;
  int wm = (widx >> 1) * 32, wn = (widx & 1) * 32;
  int n0 = blockIdx.x * 64, m0 = blockIdx.y * 64;

  f32x4 zero = {0.f, 0.f, 0.f, 0.f};
  f32x4 acc[2][2];
  acc[0][0] = zero; acc[0][1] = zero; acc[1][0] = zero; acc[1][1] = zero;

  for (int k0 = 0; k0 < p.K; k0 += 64) {
#pragma unroll
    for (int r = 0; r < 2; ++r) {
      int c = tid + 256*r;             // 0..511 : row = c>>3 (0..63), kchunk = c&7
      int row = c >> 3, kc = c & 7;
      int gk = k0 + kc*8;
      // ---- A chunk
      {
        int gm = m0 + row;
        const float* src = A + (long)gm * p.lda + gk;
        float f[8];
        if (gm < p.M && gk + 8 <= p.K) {
          float4 u0 = *(const float4*)(src);
          float4 u1 = *(const float4*)(src + 4);
          f[0]=u0.x; f[1]=u0.y; f[2]=u0.z; f[3]=u0.w;
          f[4]=u1.x; f[5]=u1.y; f[6]=u1.z; f[7]=u1.w;
        } else {
#pragma unroll
          for (int j = 0; j < 8; ++j)
            f[j] = (gm < p.M && gk + j < p.K) ? src[j] : 0.f;
        }
        short8 h;
#pragma unroll
        for (int j = 0; j < 8; ++j) h[j] = f2bf(f[j]);
        *(short8*)&As[row*72 + kc*8] = h;
      }
      // ---- B chunk
      {
        int gn = n0 + row;
        const float* src = B + (long)gn * p.ldb + gk;
        float f[8];
        if (gn < p.N && gk + 8 <= p.K) {
          float4 u0 = *(const float4*)(src);
          float4 u1 = *(const float4*)(src + 4);
          f[0]=u0.x; f[1]=u0.y; f[2]=u0.z; f[3]=u0.w;
          f[4]=u1.x; f[5]=u1.y; f[6]=u1.z; f[7]=u1.w;
        } else {
#pragma unroll
          for (int j = 0; j < 8; ++j)
            f[j] = (gn < p.N && gk + j < p.K) ? src[j] : 0.f;
        }
        short8 h;
#pragma unroll
        for (int j = 0; j < 8; ++j) h[j] = f2bf(f[j]);
        *(short8*)&Bs[row*72 + kc*8] = h;
      }
    }
    __syncthreads();
#pragma unroll
    for (int ks = 0; ks < 2; ++ks) {
      short8 a0 = *(const short8*)&As[(wm +      ln)*72 + ks*32 + quad*8];
      short8 a1 = *(const short8*)&As[(wm + 16 + ln)*72 + ks*32 + quad*8];
      short8 b0 = *(const short8*)&Bs[(wn +      ln)*72 + ks*32 + quad*8];
      short8 b1 = *(const short8*)&Bs[(wn + 16 + ln)*72 + ks*32 + quad*8];
      acc[0][0] = __builtin_amdgcn_mfma_f32_16x16x32_bf16(a0, b0, acc[0][0], 0, 0, 0);
      acc[0][1] = __builtin_amdgcn_mfma_f32_16x16x32_bf16(a0, b1, acc[0][1], 0, 0, 0);
      acc[1][0] = __builtin_amdgcn_mfma_f32_16x16x32_bf16(a1, b0, acc[1][0], 0, 0, 0);
      acc[1][1] = __builtin_amdgcn_mfma_f32_16x16x32_bf16(a1, b1, acc[1][1], 0, 0, 0);
    }
    __syncthreads();
  }

  // epilogue: C/D layout col = lane&15, row = quad*4 + reg  [verified m89/m91]
#pragma unroll
  for (int mi = 0; mi < 2; ++mi)
#pragma unroll
    for (int ni = 0; ni < 2; ++ni)
#pragma unroll
      for (int reg = 0; reg < 4; ++reg) {
        int gm = m0 + wm + mi*16 + quad*4 + reg;
        int gn = n0 + wn + ni*16 + ln;
        if (gm >= p.M || gn >= p.N) continue;
        float v = acc[mi][ni][reg] * p.alpha;
        if (TRANS) {
          C[(long)gn * p.ldc + gm] = v;
        } else {
          long co = (long)gm * p.ldc + gn;
          if (EPI == 1) v += E[gn];
          else if (EPI == 3) v = 0.5f*v*(1.f + erff(v*0.70710678118654752f));
          else if (EPI == 4) v += E[(long)gm*p.ldE + gn];
          else if (EPI == 5) v = C[co] + E[(long)(gm / p.rowsPB)*p.ldE + gn] * v;
          C[co] = v;
        }
      }
}

static GemmM mkm(const float* A, const float* B, float* C,
                 int M, int N, int K, int lda, int ldb, int ldc) {
  GemmM p; p.A = A; p.B = B; p.C = C; p.E = nullptr;
  p.M = M; p.N = N; p.K = K; p.lda = lda; p.ldb = ldb; p.ldc = ldc;
  p.sA0 = p.sA1 = p.sB0 = p.sB1 = p.sC0 = p.sC1 = 0;
  p.innerB = 1; p.ldE = 0; p.rowsPB = 1; p.alpha = 1.f;
  return p;
}

static void run_mfma(hipStream_t s, int epi, bool trans, const GemmM& p, int nb) {
  dim3 g((p.N + 63)/64, (p.M + 63)/64, nb), b(256, 1, 1);
  if (trans) { gemm_mfma<0,true><<<g,b,0,s>>>(p); return; }
  switch (epi) {
    case 0: gemm_mfma<0,false><<<g,b,0,s>>>(p); break;
    case 1: gemm_mfma<1,false><<<g,b,0,s>>>(p); break;
    case 3: gemm_mfma<3,false><<<g,b,0,s>>>(p); break;
    case 4: gemm_mfma<4,false><<<g,b,0,s>>>(p); break;
    case 5: gemm_mfma<5,false><<<g,b,0,s>>>(p); break;
  }
}

// ============================================================= small fp32 GEMM
// kept only for the tiny M=4 GEMMs (t-embedding MLP, adaLN). EPI 1 bias, 2 silu
struct GemmP {
  const float* A; const float* B; float* C; const float* E;
  int M, N, K, lda, ldb, ldc;
};

template<int EPI>
__global__ __launch_bounds__(256) void gemm_f32(GemmP p) {
  __shared__ float As[16][65];
  __shared__ float Bs[16][65];
  int tid = threadIdx.x;
  int tx = tid & 15, ty = tid >> 4;
  int n0 = blockIdx.x * 64, m0 = blockIdx.y * 64;
  float acc[4][4] = {};
  for (int k0 = 0; k0 < p.K; k0 += 16) {
#pragma unroll
    for (int r = 0; r < 4; ++r) {
      int i = tid + 256*r;
      int kk = i & 15, mm = i >> 4;
      int m = m0 + mm, k = k0 + kk;
      As[kk][mm] = (m < p.M && k < p.K) ? p.A[(long)m*p.lda + k] : 0.f;
    }
#pragma unroll
    for (int r = 0; r < 4; ++r) {
      int i = tid + 256*r;
      int kk = i & 15, nn = i >> 4;
      int n = n0 + nn, k = k0 + kk;
      Bs[kk][nn] = (n < p.N && k < p.K) ? p.B[(long)n*p.ldb + k] : 0.f;
    }
    __syncthreads();
#pragma unroll
    for (int kk = 0; kk < 16; ++kk) {
      float a[4], b[4];
#pragma unroll
      for (int i = 0; i < 4; ++i) a[i] = As[kk][ty*4+i];
#pragma unroll
      for (int j = 0; j < 4; ++j) b[j] = Bs[kk][tx*4+j];
#pragma unroll
      for (int i = 0; i < 4; ++i)
#pragma unroll
        for (int j = 0; j < 4; ++j)
          acc[i][j] += a[i]*b[j];
    }
    __syncthreads();
  }
  for (int i = 0; i < 4; ++i) {
    int m = m0 + ty*4 + i;
    if (m >= p.M) continue;
    for (int j = 0; j < 4; ++j) {
      int n = n0 + tx*4 + j;
      if (n >= p.N) continue;
      float v = acc[i][j] + p.E[n];
      if (EPI == 2) v = v / (1.f + expf(-v));
      p.C[(long)m*p.ldc + n] = v;
    }
  }
}

// ---------------------------------------------------------------- small kernels
__global__ void embed_text_cls(const float* __restrict__ Wtok, const int* __restrict__ toks,
                               const float* __restrict__ pos_text, const float* __restrict__ cls_tok,
                               float* __restrict__ x) {
  int idx = blockIdx.x*256 + threadIdx.x;           // over B*65*DIM
  int d = idx % kDim;
  int t = (idx / kDim) % (kText + 1);
  int b = idx / (kDim * (kText + 1));
  float v;
  if (t < kText) {
    int tok = toks[b*kText + t];
    v = Wtok[(long)d*kVocab + tok] + pos_text[(long)t*kDim + d];
  } else {
    v = cls_tok[d];
  }
  x[((long)b*kTok + t)*kDim + d] = v;
}

__global__ void extract_patches(const float* __restrict__ img, float* __restrict__ pat) {
  int idx = blockIdx.x*256 + threadIdx.x;           // B*256*768
  int k = idx % 768;
  int p = (idx/768) % kNp;
  int b = idx/(768*kNp);
  int c = k >> 8, py = (k >> 4) & 15, px = k & 15;
  int hp = p >> 4, wp = p & 15;
  pat[idx] = img[(((long)(b*3 + c))*kImg + hp*16 + py)*kImg + wp*16 + px];
}

__global__ void time_freqs(const int* __restrict__ ts, float* __restrict__ temb) {
  int b = blockIdx.x, i = threadIdx.x;              // 128 threads
  float f = expf(-9.210340371976184f * (float)i / 128.f);
  float a = (float)ts[b] * f;
  temb[b*kTdim + i] = cosf(a);
  temb[b*kTdim + 128 + i] = sinf(a);
}

__global__ void silu_kernel(const float* __restrict__ in, float* __restrict__ outp, int n) {
  int i = blockIdx.x*256 + threadIdx.x;
  if (i < n) { float x = in[i]; outp[i] = x / (1.f + expf(-x)); }
}

__device__ __forceinline__ float block_sum(float v) {
  __shared__ float sh[4];
  for (int off = 32; off; off >>= 1) v += __shfl_down(v, off);
  if ((threadIdx.x & 63) == 0) sh[threadIdx.x >> 6] = v;
  __syncthreads();
  float s = sh[0] + sh[1] + sh[2] + sh[3];
  __syncthreads();
  return s;
}

__global__ __launch_bounds__(256) void ln_mod_kernel(
    const float* __restrict__ x, const float* __restrict__ g, const float* __restrict__ be,
    const float* __restrict__ mod, int shOff, int scOff, float* __restrict__ outp) {
  int row = blockIdx.x;                 // b*321 + t
  int b = row / kTok;
  const float* xr = x + (long)row*kDim;
  float s = 0.f, s2 = 0.f;
  for (int i = threadIdx.x; i < kDim; i += 256) { float v = xr[i]; s += v; s2 += v*v; }
  s = block_sum(s); s2 = block_sum(s2);
  float m = s / kDim;
  float inv = rsqrtf(s2 / kDim - m*m + kEps);
  const float* mb = mod + (long)b*(6*kDim);
  for (int i = threadIdx.x; i < kDim; i += 256) {
    float xn = (xr[i] - m)*inv*g[i] + be[i];
    outp[(long)row*kDim + i] = xn*(1.f + mb[scOff + i]) + mb[shOff + i];
  }
}

__global__ __launch_bounds__(256) void final_ln_kernel(
    const float* __restrict__ x, const float* __restrict__ g, const float* __restrict__ be,
    float* __restrict__ yn) {
  int row = blockIdx.x;                 // b*256 + p
  int b = row / kNp, p = row % kNp;
  const float* xr = x + ((long)(b*kTok + kText + 1 + p))*kDim;
  float s = 0.f, s2 = 0.f;
  for (int i = threadIdx.x; i < kDim; i += 256) { float v = xr[i]; s += v; s2 += v*v; }
  s = block_sum(s); s2 = block_sum(s2);
  float m = s / kDim;
  float inv = rsqrtf(s2 / kDim - m*m + kEps);
  for (int i = threadIdx.x; i < kDim; i += 256)
    yn[(long)row*kDim + i] = (xr[i] - m)*inv*g[i] + be[i];
}

// RoPE in-place on q and k (blocks cover whole heads -> barrier makes it race-free)
__global__ __launch_bounds__(256) void rope_kernel(float* __restrict__ q, float* __restrict__ k) {
  int idx = blockIdx.x*256 + threadIdx.x;          // B*321*1024
  int d = idx & (kDim - 1);
  int n = (idx / kDim) % kTok;
  int hd = d & 63;
  int j = hd & 31;
  float inv = expf(-9.210340371976184f * (float)j / 32.f);
  float ang = (float)n * inv;
  float c = cosf(ang), s = sinf(ang);
  int base = idx - hd;
  float qv = q[idx], kv = k[idx];
  float qr, kr;
  if (hd < 32) { qr = -q[base + 2*hd + 1]; kr = -k[base + 2*hd + 1]; }
  else         { qr =  q[base + 2*(hd - 32)]; kr = k[base + 2*(hd - 32)]; }
  __syncthreads();
  q[idx] = qv*c + qr*s;
  k[idx] = kv*c + kr*s;
}

__global__ void softmax_rows(float* __restrict__ sc, int rowLen, int rowStride) {
  long row = blockIdx.x;
  float* r = sc + row*rowStride;
  int t = threadIdx.x;                              // 64 threads = 1 wave
  float mx = -1e30f;
  for (int i = t; i < rowLen; i += 64) mx = fmaxf(mx, r[i]);
  for (int off = 32; off; off >>= 1) mx = fmaxf(mx, __shfl_xor(mx, off));
  float sum = 0.f;
  for (int i = t; i < rowLen; i += 64) { float e = expf(r[i] - mx); r[i] = e; sum += e; }
  for (int off = 32; off; off >>= 1) sum += __shfl_xor(sum, off);
  float invs = 1.f / sum;
  for (int i = t; i < rowLen; i += 64) r[i] *= invs;
}

__global__ void unpatchify(const float* __restrict__ op, float* __restrict__ outp) {
  int idx = blockIdx.x*256 + threadIdx.x;           // B*3*256*256
  int w = idx & 255;
  int h = (idx >> 8) & 255;
  int c = (idx >> 16) % 3;
  int b = idx / (3 * kImg * kImg);
  int hp = h >> 4, py = h & 15, wp = w >> 4, px = w & 15;
  outp[idx] = op[((long)(b*kNp + hp*16 + wp))*768 + c*256 + py*16 + px];
}

// ---------------------------------------------------------------- launch
extern "C" void kernel_launch(void* const* d_in, const int* in_sizes, int n_in,
                              void* d_out, int out_size, void* d_ws, size_t ws_size,
                              hipStream_t stream) {
  (void)in_sizes; (void)n_in; (void)out_size; (void)ws_size;
  const float* noisy    = (const float*)d_in[0];
  const int*   toks     = (const int*)d_in[1];
  const int*   tsteps   = (const int*)d_in[2];
  const float* W_tok    = (const float*)d_in[3];
  const float* pos_text = (const float*)d_in[4];
  const float* W_patch  = (const float*)d_in[5];
  const float* pos_img  = (const float*)d_in[6];
  const float* cls_tok  = (const float*)d_in[7];
  const float* W_t1     = (const float*)d_in[8];
  const float* b_t1     = (const float*)d_in[9];
  const float* W_t2     = (const float*)d_in[10];
  const float* b_t2     = (const float*)d_in[11];
  const float* ln1_g    = (const float*)d_in[12];
  const float* ln1_b    = (const float*)d_in[13];
  const float* Wq       = (const float*)d_in[14];
  const float* Wk       = (const float*)d_in[15];
  const float* Wv       = (const float*)d_in[16];
  const float* Wo       = (const float*)d_in[17];
  const float* ln2_g    = (const float*)d_in[18];
  const float* ln2_b    = (const float*)d_in[19];
  const float* Wm1      = (const float*)d_in[20];
  const float* Wm2      = (const float*)d_in[21];
  const float* Wada     = (const float*)d_in[22];
  const float* b_ada    = (const float*)d_in[23];
  const float* fn_g     = (const float*)d_in[24];
  const float* fn_b     = (const float*)d_in[25];
  const float* W_final  = (const float*)d_in[26];
  const float* b_final  = (const float*)d_in[27];
  float* out = (float*)d_out;

  float* ws = (float*)d_ws;
  const long seqSz = (long)kBn * kTok * kDim;        // 1,314,816
  float* x    = ws;              ws += seqSz;
  float* xn   = ws;              ws += seqSz;
  float* q    = ws;              ws += seqSz;
  float* k    = ws;              ws += seqSz;
  float* o    = ws;              ws += seqSz;
  float* vt   = ws;              ws += (long)kBn*kHeads*kHd*kScLd;   // V^T [b][h][hd][tok pad]
  float* sc   = ws;              ws += (long)kBn*kHeads*kTok*kScLd;  // scores / MLP hidden
  float* pat  = ws;              ws += (long)kBn*kNp*768;            // also reused as outp
  float* temb = ws;              ws += kBn*kTdim;
  float* t1   = ws;              ws += kBn*kDim;
  float* temb2= ws;              ws += kBn*kDim;
  float* st   = ws;              ws += kBn*kDim;
  float* mod  = ws;              ws += 2L*kBn*6*kDim;
  float* yn   = ws;              ws += (long)kBn*kNp*kDim;
  float* outp = pat;             // patch buffer dead by the time final GEMM runs

  // --- embeddings
  embed_text_cls<<<(kBn*(kText+1)*kDim)/256, 256, 0, stream>>>(W_tok, toks, pos_text, cls_tok, x);
  extract_patches<<<(kBn*kNp*768)/256, 256, 0, stream>>>(noisy, pat);
  {
    GemmM p = mkm(pat, W_patch, x + (kText+1)*kDim, kNp, kDim, 768, 768, 768, kDim);
    p.sA0 = (long)kNp*768; p.sC0 = (long)kTok*kDim;
    p.E = pos_img; p.ldE = kDim;
    run_mfma(stream, 4, false, p, kBn);
  }
  // --- time embedding (tiny, fp32 path)
  time_freqs<<<kBn, 128, 0, stream>>>(tsteps, temb);
  { GemmP p{temb, W_t1, t1, b_t1, kBn, kDim, kTdim, kTdim, kTdim, kDim};
    gemm_f32<2><<<dim3(16,1,1),256,0,stream>>>(p); }
  { GemmP p{t1, W_t2, temb2, b_t2, kBn, kDim, kDim, kDim, kDim, kDim};
    gemm_f32<1><<<dim3(16,1,1),256,0,stream>>>(p); }
  silu_kernel<<<(kBn*kDim + 255)/256, 256, 0, stream>>>(temb2, st, kBn*kDim);

  for (int l = 0; l < 2; ++l) {
    const float* Wq_l  = Wq  + (long)l*kDim*kDim;
    const float* Wk_l  = Wk  + (long)l*kDim*kDim;
    const float* Wv_l  = Wv  + (long)l*kDim*kDim;
    const float* Wo_l  = Wo  + (long)l*kDim*kDim;
    const float* Wm1_l = Wm1 + (long)l*kMlp*kDim;
    const float* Wm2_l = Wm2 + (long)l*kDim*kMlp;
    float* mod_l = mod + (long)l*kBn*6*kDim;

    { GemmP p{st, Wada + (long)l*6*kDim*kDim, mod_l, b_ada + (long)l*6*kDim,
              kBn, 6*kDim, kDim, kDim, kDim, 6*kDim};
      gemm_f32<1><<<dim3(96,1,1),256,0,stream>>>(p); }

    ln_mod_kernel<<<kBn*kTok, 256, 0, stream>>>(x, ln1_g + l*kDim, ln1_b + l*kDim,
                                                mod_l, 0, kDim, xn);
    { GemmM p = mkm(xn, Wq_l, q, kBn*kTok, kDim, kDim, kDim, kDim, kDim); run_mfma(stream, 0, false, p, 1); }
    { GemmM p = mkm(xn, Wk_l, k, kBn*kTok, kDim, kDim, kDim, kDim, kDim); run_mfma(stream, 0, false, p, 1); }
    { // V projection, transposed output: vt[b][h][hd][tok(pad 328)]
      GemmM p = mkm(xn, Wv_l, vt, kTok, kDim, kDim, kDim, kDim, kScLd);
      p.sA0 = (long)kTok*kDim;
      p.sC0 = (long)kHeads*kHd*kScLd;   // per-batch block of vt
      run_mfma(stream, 0, true, p, kBn);
    }
    rope_kernel<<<(int)(seqSz/256), 256, 0, stream>>>(q, k);

    { // scores = 0.125 * q @ k^T per (b,h), rows padded to 328
      GemmM p = mkm(q, k, sc, kTok, kTok, kHd, kDim, kDim, kScLd);
      p.sA0 = (long)kTok*kDim; p.sA1 = kHd;
      p.sB0 = (long)kTok*kDim; p.sB1 = kHd;
      p.sC0 = (long)kHeads*kTok*kScLd; p.sC1 = (long)kTok*kScLd;
      p.innerB = kHeads; p.alpha = 0.125f;
      run_mfma(stream, 0, false, p, kBn*kHeads);
    }
    softmax_rows<<<kBn*kHeads*kTok, 64, 0, stream>>>(sc, kTok, kScLd);
    { // o = P @ V per (b,h): A = P (lda 328), B = vt (Bt[n=hd][k=tok], ldb 328)
      GemmM p = mkm(sc, vt, o, kTok, kHd, kTok, kScLd, kScLd, kDim);
      p.sA0 = (long)kHeads*kTok*kScLd; p.sA1 = (long)kTok*kScLd;
      p.sB0 = (long)kHeads*kHd*kScLd;  p.sB1 = (long)kHd*kScLd;
      p.sC0 = (long)kTok*kDim;         p.sC1 = kHd;
      p.innerB = kHeads;
      run_mfma(stream, 0, false, p, kBn*kHeads);
    }
    { // x += g_msa * (o @ Wo^T)
      GemmM p = mkm(o, Wo_l, x, kBn*kTok, kDim, kDim, kDim, kDim, kDim);
      p.E = mod_l + 2*kDim; p.ldE = 6*kDim; p.rowsPB = kTok;
      run_mfma(stream, 5, false, p, 1);
    }
    ln_mod_kernel<<<kBn*kTok, 256, 0, stream>>>(x, ln2_g + l*kDim, ln2_b + l*kDim,
                                                mod_l, 3*kDim, 4*kDim, xn);
    { GemmM p = mkm(xn, Wm1_l, sc, kBn*kTok, kMlp, kDim, kDim, kDim, kMlp);
      run_mfma(stream, 3, false, p, 1); }
    { GemmM p = mkm(sc, Wm2_l, x, kBn*kTok, kDim, kMlp, kMlp, kMlp, kDim);
      p.E = mod_l + 5*kDim; p.ldE = 6*kDim; p.rowsPB = kTok;
      run_mfma(stream, 5, false, p, 1); }
  }

  final_ln_kernel<<<kBn*kNp, 256, 0, stream>>>(x, fn_g, fn_b, yn);
  { GemmM p = mkm(yn, W_final, outp, kBn*kNp, 768, kDim, kDim, kDim, 768);
    p.E = b_final;
    run_mfma(stream, 1, false, p, 1); }
  unpatchify<<<(kBn*3*kImg*kImg)/256, 256, 0, stream>>>(outp, out);
}

// Round 3
// 1271.469 us; speedup vs baseline: 3.6241x; 1.3229x over previous
//
#include <hip/hip_runtime.h>
#include <hip/hip_bf16.h>
#include <math.h>

constexpr int kBn    = 4;
constexpr int kText  = 64;
constexpr int kImg   = 256;
constexpr int kDim   = 1024;
constexpr int kHeads = 16;
constexpr int kHd    = 64;
constexpr int kNp    = 256;    // patches
constexpr int kTok   = 321;    // 64 text + 1 cls + 256 img
constexpr int kVocab = 50000;
constexpr int kTdim  = 256;
constexpr int kMlp   = 4096;
constexpr int kScLd  = 328;    // score row stride (321 padded to mult of 8)
constexpr float kEps = 1e-5f;

typedef __attribute__((ext_vector_type(8))) short short8;
typedef __attribute__((ext_vector_type(4))) float f32x4;

// RNE float -> bf16 bits
__device__ __forceinline__ short f2bf(float x) {
  unsigned u = __builtin_bit_cast(unsigned, x);
  unsigned r = (u + 0x7FFFu + ((u >> 16) & 1u)) >> 16;
  return (short)r;
}

// =================================================================== MFMA GEMM
// C[m][n] = alpha * sum_k A[m][k] * Bt[n][k]  (fp32 in memory, bf16 staged)
// EPI: 0 none | 1 +bias[n] | 3 gelu | 4 +E[m][n] | 5 gated residual
// TRANS: write C[n][m]
struct GemmM {
  const float* A; const float* B; float* C; const float* E;
  int M, N, K, lda, ldb, ldc;
  long sA0, sA1, sB0, sB1, sC0, sC1;
  int innerB, ldE, rowsPB;
  float alpha;
};

template<int EPI, bool TRANS>
__global__ __launch_bounds__(256) void gemm_mfma(GemmM p) {
  int bz = blockIdx.z;
  int b1 = bz % p.innerB, b0 = bz / p.innerB;
  const float* A = p.A + b0*p.sA0 + b1*p.sA1;
  const float* B = p.B + b0*p.sB0 + b1*p.sB1;
  float* C = p.C + b0*p.sC0 + b1*p.sC1;
  const float* E = p.E;

  __shared__ short As[64*72];   // rows = m (64), cols = k (64) + pad 8
  __shared__ short Bs[64*72];   // rows = n (64), cols = k (64) + pad 8

  int tid  = threadIdx.x;
  int lane = tid & 63, widx = tid >> 6;
  int quad = lane >> 4, ln = lane & 15;
  int wm = (widx >> 1) * 32, wn = (widx & 1) * 32;
  int n0 = blockIdx.x * 64, m0 = blockIdx.y * 64;

  f32x4 zero = {0.f, 0.f, 0.f, 0.f};
  f32x4 acc[2][2];
  acc[0][0] = zero; acc[0][1] = zero; acc[1][0] = zero; acc[1][1] = zero;

  for (int k0 = 0; k0 < p.K; k0 += 64) {
#pragma unroll
    for (int r = 0; r < 2; ++r) {
      int c = tid + 256*r;             // 0..511 : row = c>>3, kchunk = c&7
      int row = c >> 3, kc = c & 7;
      int gk = k0 + kc*8;
      {
        int gm = m0 + row;
        const float* src = A + (long)gm * p.lda + gk;
        float f[8];
        if (gm < p.M && gk + 8 <= p.K) {
          float4 u0 = *(const float4*)(src);
          float4 u1 = *(const float4*)(src + 4);
          f[0]=u0.x; f[1]=u0.y; f[2]=u0.z; f[3]=u0.w;
          f[4]=u1.x; f[5]=u1.y; f[6]=u1.z; f[7]=u1.w;
        } else {
#pragma unroll
          for (int j = 0; j < 8; ++j)
            f[j] = (gm < p.M && gk + j < p.K) ? src[j] : 0.f;
        }
        short8 h;
#pragma unroll
        for (int j = 0; j < 8; ++j) h[j] = f2bf(f[j]);
        *(short8*)&As[row*72 + kc*8] = h;
      }
      {
        int gn = n0 + row;
        const float* src = B + (long)gn * p.ldb + gk;
        float f[8];
        if (gn < p.N && gk + 8 <= p.K) {
          float4 u0 = *(const float4*)(src);
          float4 u1 = *(const float4*)(src + 4);
          f[0]=u0.x; f[1]=u0.y; f[2]=u0.z; f[3]=u0.w;
          f[4]=u1.x; f[5]=u1.y; f[6]=u1.z; f[7]=u1.w;
        } else {
#pragma unroll
          for (int j = 0; j < 8; ++j)
            f[j] = (gn < p.N && gk + j < p.K) ? src[j] : 0.f;
        }
        short8 h;
#pragma unroll
        for (int j = 0; j < 8; ++j) h[j] = f2bf(f[j]);
        *(short8*)&Bs[row*72 + kc*8] = h;
      }
    }
    __syncthreads();
#pragma unroll
    for (int ks = 0; ks < 2; ++ks) {
      short8 a0 = *(const short8*)&As[(wm +      ln)*72 + ks*32 + quad*8];
      short8 a1 = *(const short8*)&As[(wm + 16 + ln)*72 + ks*32 + quad*8];
      short8 b0 = *(const short8*)&Bs[(wn +      ln)*72 + ks*32 + quad*8];
      short8 b1 = *(const short8*)&Bs[(wn + 16 + ln)*72 + ks*32 + quad*8];
      acc[0][0] = __builtin_amdgcn_mfma_f32_16x16x32_bf16(a0, b0, acc[0][0], 0, 0, 0);
      acc[0][1] = __builtin_amdgcn_mfma_f32_16x16x32_bf16(a0, b1, acc[0][1], 0, 0, 0);
      acc[1][0] = __builtin_amdgcn_mfma_f32_16x16x32_bf16(a1, b0, acc[1][0], 0, 0, 0);
      acc[1][1] = __builtin_amdgcn_mfma_f32_16x16x32_bf16(a1, b1, acc[1][1], 0, 0, 0);
    }
    __syncthreads();
  }

  // C/D layout: col = lane&15, row = quad*4 + reg  [verified m89/m91]
#pragma unroll
  for (int mi = 0; mi < 2; ++mi)
#pragma unroll
    for (int ni = 0; ni < 2; ++ni)
#pragma unroll
      for (int reg = 0; reg < 4; ++reg) {
        int gm = m0 + wm + mi*16 + quad*4 + reg;
        int gn = n0 + wn + ni*16 + ln;
        if (gm >= p.M || gn >= p.N) continue;
        float v = acc[mi][ni][reg] * p.alpha;
        if (TRANS) {
          C[(long)gn * p.ldc + gm] = v;
        } else {
          long co = (long)gm * p.ldc + gn;
          if (EPI == 1) v += E[gn];
          else if (EPI == 3) v = 0.5f*v*(1.f + erff(v*0.70710678118654752f));
          else if (EPI == 4) v += E[(long)gm*p.ldE + gn];
          else if (EPI == 5) v = C[co] + E[(long)(gm / p.rowsPB)*p.ldE + gn] * v;
          C[co] = v;
        }
      }
}

static GemmM mkm(const float* A, const float* B, float* C,
                 int M, int N, int K, int lda, int ldb, int ldc) {
  GemmM p; p.A = A; p.B = B; p.C = C; p.E = nullptr;
  p.M = M; p.N = N; p.K = K; p.lda = lda; p.ldb = ldb; p.ldc = ldc;
  p.sA0 = p.sA1 = p.sB0 = p.sB1 = p.sC0 = p.sC1 = 0;
  p.innerB = 1; p.ldE = 0; p.rowsPB = 1; p.alpha = 1.f;
  return p;
}

static void run_mfma(hipStream_t s, int epi, bool trans, const GemmM& p, int nb) {
  dim3 g((p.N + 63)/64, (p.M + 63)/64, nb), b(256, 1, 1);
  if (trans) { gemm_mfma<0,true><<<g,b,0,s>>>(p); return; }
  switch (epi) {
    case 0: gemm_mfma<0,false><<<g,b,0,s>>>(p); break;
    case 1: gemm_mfma<1,false><<<g,b,0,s>>>(p); break;
    case 3: gemm_mfma<3,false><<<g,b,0,s>>>(p); break;
    case 4: gemm_mfma<4,false><<<g,b,0,s>>>(p); break;
    case 5: gemm_mfma<5,false><<<g,b,0,s>>>(p); break;
  }
}

// ================================================================ skinny GEMV4
// C[m][n] = dot(A[m][:], B[n][:]) + bias[n], m = 0..3.  One wave per n.
// EPI: 1 bias | 2 silu(bias).  Memory-bound on reading B once.
template<int EPI>
__global__ __launch_bounds__(256) void gemv4(const float* __restrict__ A,
                                             const float* __restrict__ B,
                                             float* __restrict__ C,
                                             const float* __restrict__ bias,
                                             int N, int K, int ldc) {
  int wave = threadIdx.x >> 6, lane = threadIdx.x & 63;
  int n = blockIdx.x * 4 + wave;
  if (n >= N) return;
  const float* Brow = B + (long)n * K;
  float acc0 = 0.f, acc1 = 0.f, acc2 = 0.f, acc3 = 0.f;
  for (int k = lane * 4; k < K; k += 256) {
    float4 b = *(const float4*)(Brow + k);
    float4 a0 = *(const float4*)(A + 0*K + k);
    float4 a1 = *(const float4*)(A + 1*K + k);
    float4 a2 = *(const float4*)(A + 2*K + k);
    float4 a3 = *(const float4*)(A + 3*K + k);
    acc0 += a0.x*b.x + a0.y*b.y + a0.z*b.z + a0.w*b.w;
    acc1 += a1.x*b.x + a1.y*b.y + a1.z*b.z + a1.w*b.w;
    acc2 += a2.x*b.x + a2.y*b.y + a2.z*b.z + a2.w*b.w;
    acc3 += a3.x*b.x + a3.y*b.y + a3.z*b.z + a3.w*b.w;
  }
#pragma unroll
  for (int off = 32; off; off >>= 1) {
    acc0 += __shfl_xor(acc0, off);
    acc1 += __shfl_xor(acc1, off);
    acc2 += __shfl_xor(acc2, off);
    acc3 += __shfl_xor(acc3, off);
  }
  if (lane == 0) {
    float bs = bias[n];
    float v[4] = {acc0 + bs, acc1 + bs, acc2 + bs, acc3 + bs};
#pragma unroll
    for (int m = 0; m < 4; ++m) {
      float x = v[m];
      if (EPI == 2) x = x / (1.f + expf(-x));
      C[(long)m * ldc + n] = x;
    }
  }
}

// ---------------------------------------------------------------- small kernels
__global__ void embed_text_cls(const float* __restrict__ Wtok, const int* __restrict__ toks,
                               const float* __restrict__ pos_text, const float* __restrict__ cls_tok,
                               float* __restrict__ x) {
  int idx = blockIdx.x*256 + threadIdx.x;           // over B*65*DIM
  int d = idx % kDim;
  int t = (idx / kDim) % (kText + 1);
  int b = idx / (kDim * (kText + 1));
  float v;
  if (t < kText) {
    int tok = toks[b*kText + t];
    v = Wtok[(long)d*kVocab + tok] + pos_text[(long)t*kDim + d];
  } else {
    v = cls_tok[d];
  }
  x[((long)b*kTok + t)*kDim + d] = v;
}

__global__ void extract_patches(const float* __restrict__ img, float* __restrict__ pat) {
  int idx = blockIdx.x*256 + threadIdx.x;           // B*256*768
  int k = idx % 768;
  int p = (idx/768) % kNp;
  int b = idx/(768*kNp);
  int c = k >> 8, py = (k >> 4) & 15, px = k & 15;
  int hp = p >> 4, wp = p & 15;
  pat[idx] = img[(((long)(b*3 + c))*kImg + hp*16 + py)*kImg + wp*16 + px];
}

__global__ void time_freqs(const int* __restrict__ ts, float* __restrict__ temb) {
  int b = blockIdx.x, i = threadIdx.x;              // 128 threads
  float f = expf(-9.210340371976184f * (float)i / 128.f);
  float a = (float)ts[b] * f;
  temb[b*kTdim + i] = cosf(a);
  temb[b*kTdim + 128 + i] = sinf(a);
}

__global__ void silu_kernel(const float* __restrict__ in, float* __restrict__ outp, int n) {
  int i = blockIdx.x*256 + threadIdx.x;
  if (i < n) { float x = in[i]; outp[i] = x / (1.f + expf(-x)); }
}

__device__ __forceinline__ float block_sum(float v) {
  __shared__ float sh[4];
  for (int off = 32; off; off >>= 1) v += __shfl_down(v, off);
  if ((threadIdx.x & 63) == 0) sh[threadIdx.x >> 6] = v;
  __syncthreads();
  float s = sh[0] + sh[1] + sh[2] + sh[3];
  __syncthreads();
  return s;
}

__global__ __launch_bounds__(256) void ln_mod_kernel(
    const float* __restrict__ x, const float* __restrict__ g, const float* __restrict__ be,
    const float* __restrict__ mod, int shOff, int scOff, float* __restrict__ outp) {
  int row = blockIdx.x;                 // b*321 + t
  int b = row / kTok;
  const float* xr = x + (long)row*kDim;
  float s = 0.f, s2 = 0.f;
  for (int i = threadIdx.x; i < kDim; i += 256) { float v = xr[i]; s += v; s2 += v*v; }
  s = block_sum(s); s2 = block_sum(s2);
  float m = s / kDim;
  float inv = rsqrtf(s2 / kDim - m*m + kEps);
  const float* mb = mod + (long)b*(6*kDim);
  for (int i = threadIdx.x; i < kDim; i += 256) {
    float xn = (xr[i] - m)*inv*g[i] + be[i];
    outp[(long)row*kDim + i] = xn*(1.f + mb[scOff + i]) + mb[shOff + i];
  }
}

__global__ __launch_bounds__(256) void final_ln_kernel(
    const float* __restrict__ x, const float* __restrict__ g, const float* __restrict__ be,
    float* __restrict__ yn) {
  int row = blockIdx.x;                 // b*256 + p
  int b = row / kNp, p = row % kNp;
  const float* xr = x + ((long)(b*kTok + kText + 1 + p))*kDim;
  float s = 0.f, s2 = 0.f;
  for (int i = threadIdx.x; i < kDim; i += 256) { float v = xr[i]; s += v; s2 += v*v; }
  s = block_sum(s); s2 = block_sum(s2);
  float m = s / kDim;
  float inv = rsqrtf(s2 / kDim - m*m + kEps);
  for (int i = threadIdx.x; i < kDim; i += 256)
    yn[(long)row*kDim + i] = (xr[i] - m)*inv*g[i] + be[i];
}

// RoPE in-place on q and k (blocks cover whole heads -> barrier makes it race-free)
__global__ __launch_bounds__(256) void rope_kernel(float* __restrict__ q, float* __restrict__ k) {
  int idx = blockIdx.x*256 + threadIdx.x;          // B*321*1024
  int d = idx & (kDim - 1);
  int n = (idx / kDim) % kTok;
  int hd = d & 63;
  int j = hd & 31;
  float inv = expf(-9.210340371976184f * (float)j / 32.f);
  float ang = (float)n * inv;
  float c = cosf(ang), s = sinf(ang);
  int base = idx - hd;
  float qv = q[idx], kv = k[idx];
  float qr, kr;
  if (hd < 32) { qr = -q[base + 2*hd + 1]; kr = -k[base + 2*hd + 1]; }
  else         { qr =  q[base + 2*(hd - 32)]; kr = k[base + 2*(hd - 32)]; }
  __syncthreads();
  q[idx] = qv*c + qr*s;
  k[idx] = kv*c + kr*s;
}

__global__ void softmax_rows(float* __restrict__ sc, int rowLen, int rowStride) {
  long row = blockIdx.x;
  float* r = sc + row*rowStride;
  int t = threadIdx.x;                              // 64 threads = 1 wave
  float mx = -1e30f;
  for (int i = t; i < rowLen; i += 64) mx = fmaxf(mx, r[i]);
  for (int off = 32; off; off >>= 1) mx = fmaxf(mx, __shfl_xor(mx, off));
  float sum = 0.f;
  for (int i = t; i < rowLen; i += 64) { float e = expf(r[i] - mx); r[i] = e; sum += e; }
  for (int off = 32; off; off >>= 1) sum += __shfl_xor(sum, off);
  float invs = 1.f / sum;
  for (int i = t; i < rowLen; i += 64) r[i] *= invs;
}

__global__ void unpatchify(const float* __restrict__ op, float* __restrict__ outp) {
  int idx = blockIdx.x*256 + threadIdx.x;           // B*3*256*256
  int w = idx & 255;
  int h = (idx >> 8) & 255;
  int c = (idx >> 16) % 3;
  int b = idx / (3 * kImg * kImg);
  int hp = h >> 4, py = h & 15, wp = w >> 4, px = w & 15;
  outp[idx] = op[((long)(b*kNp + hp*16 + wp))*768 + c*256 + py*16 + px];
}

// ---------------------------------------------------------------- launch
extern "C" void kernel_launch(void* const* d_in, const int* in_sizes, int n_in,
                              void* d_out, int out_size, void* d_ws, size_t ws_size,
                              hipStream_t stream) {
  (void)in_sizes; (void)n_in; (void)out_size; (void)ws_size;
  const float* noisy    = (const float*)d_in[0];
  const int*   toks     = (const int*)d_in[1];
  const int*   tsteps   = (const int*)d_in[2];
  const float* W_tok    = (const float*)d_in[3];
  const float* pos_text = (const float*)d_in[4];
  const float* W_patch  = (const float*)d_in[5];
  const float* pos_img  = (const float*)d_in[6];
  const float* cls_tok  = (const float*)d_in[7];
  const float* W_t1     = (const float*)d_in[8];
  const float* b_t1     = (const float*)d_in[9];
  const float* W_t2     = (const float*)d_in[10];
  const float* b_t2     = (const float*)d_in[11];
  const float* ln1_g    = (const float*)d_in[12];
  const float* ln1_b    = (const float*)d_in[13];
  const float* Wq       = (const float*)d_in[14];
  const float* Wk       = (const float*)d_in[15];
  const float* Wv       = (const float*)d_in[16];
  const float* Wo       = (const float*)d_in[17];
  const float* ln2_g    = (const float*)d_in[18];
  const float* ln2_b    = (const float*)d_in[19];
  const float* Wm1      = (const float*)d_in[20];
  const float* Wm2      = (const float*)d_in[21];
  const float* Wada     = (const float*)d_in[22];
  const float* b_ada    = (const float*)d_in[23];
  const float* fn_g     = (const float*)d_in[24];
  const float* fn_b     = (const float*)d_in[25];
  const float* W_final  = (const float*)d_in[26];
  const float* b_final  = (const float*)d_in[27];
  float* out = (float*)d_out;

  float* ws = (float*)d_ws;
  const long seqSz = (long)kBn * kTok * kDim;        // 1,314,816
  float* x    = ws;              ws += seqSz;
  float* xn   = ws;              ws += seqSz;
  float* q    = ws;              ws += seqSz;
  float* k    = ws;              ws += seqSz;
  float* o    = ws;              ws += seqSz;
  float* vt   = ws;              ws += (long)kBn*kHeads*kHd*kScLd;   // V^T [b][h][hd][tok pad]
  float* sc   = ws;              ws += (long)kBn*kHeads*kTok*kScLd;  // scores / MLP hidden
  float* pat  = ws;              ws += (long)kBn*kNp*768;            // also reused as outp
  float* temb = ws;              ws += kBn*kTdim;
  float* t1   = ws;              ws += kBn*kDim;
  float* temb2= ws;              ws += kBn*kDim;
  float* st   = ws;              ws += kBn*kDim;
  float* mod  = ws;              ws += 2L*kBn*6*kDim;
  float* yn   = ws;              ws += (long)kBn*kNp*kDim;
  float* outp = pat;             // patch buffer dead by the time final GEMM runs

  // --- embeddings
  embed_text_cls<<<(kBn*(kText+1)*kDim)/256, 256, 0, stream>>>(W_tok, toks, pos_text, cls_tok, x);
  extract_patches<<<(kBn*kNp*768)/256, 256, 0, stream>>>(noisy, pat);
  {
    GemmM p = mkm(pat, W_patch, x + (kText+1)*kDim, kNp, kDim, 768, 768, 768, kDim);
    p.sA0 = (long)kNp*768; p.sC0 = (long)kTok*kDim;
    p.E = pos_img; p.ldE = kDim;
    run_mfma(stream, 4, false, p, kBn);
  }
  // --- time embedding (skinny GEMV path)
  time_freqs<<<kBn, 128, 0, stream>>>(tsteps, temb);
  gemv4<2><<<kDim/4, 256, 0, stream>>>(temb, W_t1, t1, b_t1, kDim, kTdim, kDim);
  gemv4<1><<<kDim/4, 256, 0, stream>>>(t1, W_t2, temb2, b_t2, kDim, kDim, kDim);
  silu_kernel<<<(kBn*kDim + 255)/256, 256, 0, stream>>>(temb2, st, kBn*kDim);

  for (int l = 0; l < 2; ++l) {
    const float* Wq_l  = Wq  + (long)l*kDim*kDim;
    const float* Wk_l  = Wk  + (long)l*kDim*kDim;
    const float* Wv_l  = Wv  + (long)l*kDim*kDim;
    const float* Wo_l  = Wo  + (long)l*kDim*kDim;
    const float* Wm1_l = Wm1 + (long)l*kMlp*kDim;
    const float* Wm2_l = Wm2 + (long)l*kDim*kMlp;
    float* mod_l = mod + (long)l*kBn*6*kDim;

    gemv4<1><<<(6*kDim)/4, 256, 0, stream>>>(st, Wada + (long)l*6*kDim*kDim, mod_l,
                                             b_ada + (long)l*6*kDim, 6*kDim, kDim, 6*kDim);

    ln_mod_kernel<<<kBn*kTok, 256, 0, stream>>>(x, ln1_g + l*kDim, ln1_b + l*kDim,
                                                mod_l, 0, kDim, xn);
    { GemmM p = mkm(xn, Wq_l, q, kBn*kTok, kDim, kDim, kDim, kDim, kDim); run_mfma(stream, 0, false, p, 1); }
    { GemmM p = mkm(xn, Wk_l, k, kBn*kTok, kDim, kDim, kDim, kDim, kDim); run_mfma(stream, 0, false, p, 1); }
    { // V projection, transposed output: vt[b][h][hd][tok(pad 328)]
      GemmM p = mkm(xn, Wv_l, vt, kTok, kDim, kDim, kDim, kDim, kScLd);
      p.sA0 = (long)kTok*kDim;
      p.sC0 = (long)kHeads*kHd*kScLd;
      run_mfma(stream, 0, true, p, kBn);
    }
    rope_kernel<<<(int)(seqSz/256), 256, 0, stream>>>(q, k);

    { // scores = 0.125 * q @ k^T per (b,h), rows padded to 328
      GemmM p = mkm(q, k, sc, kTok, kTok, kHd, kDim, kDim, kScLd);
      p.sA0 = (long)kTok*kDim; p.sA1 = kHd;
      p.sB0 = (long)kTok*kDim; p.sB1 = kHd;
      p.sC0 = (long)kHeads*kTok*kScLd; p.sC1 = (long)kTok*kScLd;
      p.innerB = kHeads; p.alpha = 0.125f;
      run_mfma(stream, 0, false, p, kBn*kHeads);
    }
    softmax_rows<<<kBn*kHeads*kTok, 64, 0, stream>>>(sc, kTok, kScLd);
    { // o = P @ V per (b,h)
      GemmM p = mkm(sc, vt, o, kTok, kHd, kTok, kScLd, kScLd, kDim);
      p.sA0 = (long)kHeads*kTok*kScLd; p.sA1 = (long)kTok*kScLd;
      p.sB0 = (long)kHeads*kHd*kScLd;  p.sB1 = (long)kHd*kScLd;
      p.sC0 = (long)kTok*kDim;         p.sC1 = kHd;
      p.innerB = kHeads;
      run_mfma(stream, 0, false, p, kBn*kHeads);
    }
    { // x += g_msa * (o @ Wo^T)
      GemmM p = mkm(o, Wo_l, x, kBn*kTok, kDim, kDim, kDim, kDim, kDim);
      p.E = mod_l + 2*kDim; p.ldE = 6*kDim; p.rowsPB = kTok;
      run_mfma(stream, 5, false, p, 1);
    }
    ln_mod_kernel<<<kBn*kTok, 256, 0, stream>>>(x, ln2_g + l*kDim, ln2_b + l*kDim,
                                                mod_l, 3*kDim, 4*kDim, xn);
    { GemmM p = mkm(xn, Wm1_l, sc, kBn*kTok, kMlp, kDim, kDim, kDim, kMlp);
      run_mfma(stream, 3, false, p, 1); }
    { GemmM p = mkm(sc, Wm2_l, x, kBn*kTok, kDim, kMlp, kMlp, kMlp, kDim);
      p.E = mod_l + 5*kDim; p.ldE = 6*kDim; p.rowsPB = kTok;
      run_mfma(stream, 5, false, p, 1); }
  }

  final_ln_kernel<<<kBn*kNp, 256, 0, stream>>>(x, fn_g, fn_b, yn);
  { GemmM p = mkm(yn, W_final, outp, kBn*kNp, 768, kDim, kDim, kDim, 768);
    p.E = b_final;
    run_mfma(stream, 1, false, p, 1); }
  unpatchify<<<(kBn*3*kImg*kImg)/256, 256, 0, stream>>>(outp, out);
}

// Round 4
// 1240.376 us; speedup vs baseline: 3.7149x; 1.0251x over previous
//
#include <hip/hip_runtime.h>
#include <hip/hip_bf16.h>
#include <math.h>

constexpr int kBn    = 4;
constexpr int kText  = 64;
constexpr int kImg   = 256;
constexpr int kDim   = 1024;
constexpr int kHeads = 16;
constexpr int kHd    = 64;
constexpr int kNp    = 256;    // patches
constexpr int kTok   = 321;    // 64 text + 1 cls + 256 img
constexpr int kVocab = 50000;
constexpr int kTdim  = 256;
constexpr int kMlp   = 4096;
constexpr int kScLd  = 328;    // score row stride (321 padded to mult of 8)
constexpr float kEps = 1e-5f;

typedef __attribute__((ext_vector_type(8))) short short8;
typedef __attribute__((ext_vector_type(4))) float f32x4;

// RNE float -> bf16 bits
__device__ __forceinline__ short f2bf(float x) {
  unsigned u = __builtin_bit_cast(unsigned, x);
  unsigned r = (u + 0x7FFFu + ((u >> 16) & 1u)) >> 16;
  return (short)r;
}

// =================================================================== MFMA GEMM
// C[m][n] = alpha * sum_k A[m][k] * Bt[n][k]  (fp32 in memory, bf16 staged)
// EPI: 0 none | 1 +bias[n] | 3 gelu | 4 +E[m][n] | 5 gated residual
// TRANS: write C[n][m].  PART: split-K partial, raw write to C + split*partStride.
struct GemmM {
  const float* A; const float* B; float* C; const float* E;
  int M, N, K, lda, ldb, ldc;
  long sA0, sA1, sB0, sB1, sC0, sC1;
  int innerB, ldE, rowsPB;
  float alpha;
  int nSplit, splitLen;
  long partStride;
};

template<int EPI, bool TRANS, bool PART>
__global__ __launch_bounds__(256) void gemm_mfma(GemmM p) {
  int bz = blockIdx.z;
  int split = 0;
  if (PART) { split = bz % p.nSplit; bz /= p.nSplit; }
  int b1 = bz % p.innerB, b0 = bz / p.innerB;
  const float* A = p.A + b0*p.sA0 + b1*p.sA1;
  const float* B = p.B + b0*p.sB0 + b1*p.sB1;
  float* C = p.C + b0*p.sC0 + b1*p.sC1 + (PART ? (long)split * p.partStride : 0);
  const float* E = p.E;

  int kBeg = PART ? split * p.splitLen : 0;
  int kEnd = PART ? min(p.K, kBeg + p.splitLen) : p.K;

  __shared__ short As[64*72];   // rows = m (64), cols = k (64) + pad 8
  __shared__ short Bs[64*72];   // rows = n (64), cols = k (64) + pad 8

  int tid  = threadIdx.x;
  int lane = tid & 63, widx = tid >> 6;
  int quad = lane >> 4, ln = lane & 15;
  int wm = (widx >> 1) * 32, wn = (widx & 1) * 32;
  int n0 = blockIdx.x * 64, m0 = blockIdx.y * 64;

  f32x4 zero = {0.f, 0.f, 0.f, 0.f};
  f32x4 acc[2][2];
  acc[0][0] = zero; acc[0][1] = zero; acc[1][0] = zero; acc[1][1] = zero;

  float fa[2][8], fb[2][8];
  auto issueLoads = [&](int k0) {
#pragma unroll
    for (int r = 0; r < 2; ++r) {
      int c = tid + 256*r;              // row = c>>3 (0..63), kchunk = c&7
      int row = c >> 3, kc = c & 7;
      int gk = k0 + kc*8;
      {
        int gm = m0 + row;
        const float* src = A + (long)gm * p.lda + gk;
        if (gm < p.M && gk + 8 <= kEnd) {
          float4 u0 = *(const float4*)(src);
          float4 u1 = *(const float4*)(src + 4);
          fa[r][0]=u0.x; fa[r][1]=u0.y; fa[r][2]=u0.z; fa[r][3]=u0.w;
          fa[r][4]=u1.x; fa[r][5]=u1.y; fa[r][6]=u1.z; fa[r][7]=u1.w;
        } else {
#pragma unroll
          for (int j = 0; j < 8; ++j)
            fa[r][j] = (gm < p.M && gk + j < kEnd) ? src[j] : 0.f;
        }
      }
      {
        int gn = n0 + row;
        const float* src = B + (long)gn * p.ldb + gk;
        if (gn < p.N && gk + 8 <= kEnd) {
          float4 u0 = *(const float4*)(src);
          float4 u1 = *(const float4*)(src + 4);
          fb[r][0]=u0.x; fb[r][1]=u0.y; fb[r][2]=u0.z; fb[r][3]=u0.w;
          fb[r][4]=u1.x; fb[r][5]=u1.y; fb[r][6]=u1.z; fb[r][7]=u1.w;
        } else {
#pragma unroll
          for (int j = 0; j < 8; ++j)
            fb[r][j] = (gn < p.N && gk + j < kEnd) ? src[j] : 0.f;
        }
      }
    }
  };

  issueLoads(kBeg);
  for (int k0 = kBeg; k0 < kEnd; k0 += 64) {
#pragma unroll
    for (int r = 0; r < 2; ++r) {
      int c = tid + 256*r;
      int row = c >> 3, kc = c & 7;
      short8 ha, hb;
#pragma unroll
      for (int j = 0; j < 8; ++j) { ha[j] = f2bf(fa[r][j]); hb[j] = f2bf(fb[r][j]); }
      *(short8*)&As[row*72 + kc*8] = ha;
      *(short8*)&Bs[row*72 + kc*8] = hb;
    }
    __syncthreads();
    if (k0 + 64 < kEnd) issueLoads(k0 + 64);   // prefetch next stage into regs
#pragma unroll
    for (int ks = 0; ks < 2; ++ks) {
      short8 a0 = *(const short8*)&As[(wm +      ln)*72 + ks*32 + quad*8];
      short8 a1 = *(const short8*)&As[(wm + 16 + ln)*72 + ks*32 + quad*8];
      short8 b0 = *(const short8*)&Bs[(wn +      ln)*72 + ks*32 + quad*8];
      short8 b1 = *(const short8*)&Bs[(wn + 16 + ln)*72 + ks*32 + quad*8];
      acc[0][0] = __builtin_amdgcn_mfma_f32_16x16x32_bf16(a0, b0, acc[0][0], 0, 0, 0);
      acc[0][1] = __builtin_amdgcn_mfma_f32_16x16x32_bf16(a0, b1, acc[0][1], 0, 0, 0);
      acc[1][0] = __builtin_amdgcn_mfma_f32_16x16x32_bf16(a1, b0, acc[1][0], 0, 0, 0);
      acc[1][1] = __builtin_amdgcn_mfma_f32_16x16x32_bf16(a1, b1, acc[1][1], 0, 0, 0);
    }
    __syncthreads();
  }

  // C/D layout: col = lane&15, row = quad*4 + reg  [verified m89/m91]
#pragma unroll
  for (int mi = 0; mi < 2; ++mi)
#pragma unroll
    for (int ni = 0; ni < 2; ++ni)
#pragma unroll
      for (int reg = 0; reg < 4; ++reg) {
        int gm = m0 + wm + mi*16 + quad*4 + reg;
        int gn = n0 + wn + ni*16 + ln;
        if (gm >= p.M || gn >= p.N) continue;
        float v = acc[mi][ni][reg] * p.alpha;
        if (TRANS) {
          C[(long)gn * p.ldc + gm] = v;
        } else {
          long co = (long)gm * p.ldc + gn;
          if (!PART) {
            if (EPI == 1) v += E[gn];
            else if (EPI == 3) v = 0.5f*v*(1.f + erff(v*0.70710678118654752f));
            else if (EPI == 4) v += E[(long)gm*p.ldE + gn];
            else if (EPI == 5) v = C[co] + E[(long)(gm / p.rowsPB)*p.ldE + gn] * v;
          }
          C[co] = v;
        }
      }
}

static GemmM mkm(const float* A, const float* B, float* C,
                 int M, int N, int K, int lda, int ldb, int ldc) {
  GemmM p; p.A = A; p.B = B; p.C = C; p.E = nullptr;
  p.M = M; p.N = N; p.K = K; p.lda = lda; p.ldb = ldb; p.ldc = ldc;
  p.sA0 = p.sA1 = p.sB0 = p.sB1 = p.sC0 = p.sC1 = 0;
  p.innerB = 1; p.ldE = 0; p.rowsPB = 1; p.alpha = 1.f;
  p.nSplit = 1; p.splitLen = 0; p.partStride = 0;
  return p;
}

static void run_mfma(hipStream_t s, int epi, bool trans, const GemmM& p, int nb) {
  dim3 g((p.N + 63)/64, (p.M + 63)/64, nb), b(256, 1, 1);
  if (trans) { gemm_mfma<0,true,false><<<g,b,0,s>>>(p); return; }
  switch (epi) {
    case 0: gemm_mfma<0,false,false><<<g,b,0,s>>>(p); break;
    case 1: gemm_mfma<1,false,false><<<g,b,0,s>>>(p); break;
    case 3: gemm_mfma<3,false,false><<<g,b,0,s>>>(p); break;
    case 4: gemm_mfma<4,false,false><<<g,b,0,s>>>(p); break;
    case 5: gemm_mfma<5,false,false><<<g,b,0,s>>>(p); break;
  }
}

static void run_mfma_part(hipStream_t s, bool trans, const GemmM& p, int nb) {
  dim3 g((p.N + 63)/64, (p.M + 63)/64, nb * p.nSplit), b(256, 1, 1);
  if (trans) gemm_mfma<0,true,true><<<g,b,0,s>>>(p);
  else       gemm_mfma<0,false,true><<<g,b,0,s>>>(p);
}

// ------------------------------------------------------------- split-K reduce
template<int EPI>
__global__ __launch_bounds__(256) void reduce_split(
    const float* __restrict__ part, long partStride, int S,
    float* __restrict__ C, const float* __restrict__ E,
    int Mv, int Nv, int ldc, long sC0, long sC1, int innerB,
    int ldE, int rowsPB, int total) {
  int idx = blockIdx.x*256 + threadIdx.x;
  if (idx >= total) return;
  int n = idx % Nv;
  int m = (idx / Nv) % Mv;
  int bz = idx / (Nv * Mv);
  int b1 = bz % innerB, b0 = bz / innerB;
  long co = b0*sC0 + b1*sC1 + (long)m*ldc + n;
  float v = 0.f;
  for (int s = 0; s < S; ++s) v += part[(long)s*partStride + co];
  if (EPI == 1) v += E[n];
  else if (EPI == 3) v = 0.5f*v*(1.f + erff(v*0.70710678118654752f));
  else if (EPI == 4) v += E[(long)m*ldE + n];
  else if (EPI == 5) v = C[co] + E[(long)(m / rowsPB)*ldE + n] * v;
  C[co] = v;
}

static void run_reduce(hipStream_t st, int epi, const float* part, long pStride, int S,
                       float* C, const float* E, int Mv, int Nv, int ldc,
                       long sC0, long sC1, int innerB, int nbTot, int ldE, int rowsPB) {
  int total = nbTot * Mv * Nv;
  dim3 g((total + 255)/256), b(256);
  switch (epi) {
    case 0: reduce_split<0><<<g,b,0,st>>>(part,pStride,S,C,E,Mv,Nv,ldc,sC0,sC1,innerB,ldE,rowsPB,total); break;
    case 1: reduce_split<1><<<g,b,0,st>>>(part,pStride,S,C,E,Mv,Nv,ldc,sC0,sC1,innerB,ldE,rowsPB,total); break;
    case 3: reduce_split<3><<<g,b,0,st>>>(part,pStride,S,C,E,Mv,Nv,ldc,sC0,sC1,innerB,ldE,rowsPB,total); break;
    case 4: reduce_split<4><<<g,b,0,st>>>(part,pStride,S,C,E,Mv,Nv,ldc,sC0,sC1,innerB,ldE,rowsPB,total); break;
    case 5: reduce_split<5><<<g,b,0,st>>>(part,pStride,S,C,E,Mv,Nv,ldc,sC0,sC1,innerB,ldE,rowsPB,total); break;
  }
}

// ================================================================ skinny GEMV4
template<int EPI>
__global__ __launch_bounds__(256) void gemv4(const float* __restrict__ A,
                                             const float* __restrict__ B,
                                             float* __restrict__ C,
                                             const float* __restrict__ bias,
                                             int N, int K, int ldc) {
  int wave = threadIdx.x >> 6, lane = threadIdx.x & 63;
  int n = blockIdx.x * 4 + wave;
  if (n >= N) return;
  const float* Brow = B + (long)n * K;
  float acc0 = 0.f, acc1 = 0.f, acc2 = 0.f, acc3 = 0.f;
  for (int k = lane * 4; k < K; k += 256) {
    float4 b = *(const float4*)(Brow + k);
    float4 a0 = *(const float4*)(A + 0*K + k);
    float4 a1 = *(const float4*)(A + 1*K + k);
    float4 a2 = *(const float4*)(A + 2*K + k);
    float4 a3 = *(const float4*)(A + 3*K + k);
    acc0 += a0.x*b.x + a0.y*b.y + a0.z*b.z + a0.w*b.w;
    acc1 += a1.x*b.x + a1.y*b.y + a1.z*b.z + a1.w*b.w;
    acc2 += a2.x*b.x + a2.y*b.y + a2.z*b.z + a2.w*b.w;
    acc3 += a3.x*b.x + a3.y*b.y + a3.z*b.z + a3.w*b.w;
  }
#pragma unroll
  for (int off = 32; off; off >>= 1) {
    acc0 += __shfl_xor(acc0, off);
    acc1 += __shfl_xor(acc1, off);
    acc2 += __shfl_xor(acc2, off);
    acc3 += __shfl_xor(acc3, off);
  }
  if (lane == 0) {
    float bs = bias[n];
    float v[4] = {acc0 + bs, acc1 + bs, acc2 + bs, acc3 + bs};
#pragma unroll
    for (int m = 0; m < 4; ++m) {
      float x = v[m];
      if (EPI == 2) x = x / (1.f + expf(-x));
      C[(long)m * ldc + n] = x;
    }
  }
}

// ---------------------------------------------------------------- small kernels
__global__ void embed_text_cls(const float* __restrict__ Wtok, const int* __restrict__ toks,
                               const float* __restrict__ pos_text, const float* __restrict__ cls_tok,
                               float* __restrict__ x) {
  int idx = blockIdx.x*256 + threadIdx.x;           // over B*65*DIM
  int d = idx % kDim;
  int t = (idx / kDim) % (kText + 1);
  int b = idx / (kDim * (kText + 1));
  float v;
  if (t < kText) {
    int tok = toks[b*kText + t];
    v = Wtok[(long)d*kVocab + tok] + pos_text[(long)t*kDim + d];
  } else {
    v = cls_tok[d];
  }
  x[((long)b*kTok + t)*kDim + d] = v;
}

__global__ void extract_patches(const float* __restrict__ img, float* __restrict__ pat) {
  int idx = blockIdx.x*256 + threadIdx.x;           // B*256*768
  int k = idx % 768;
  int p = (idx/768) % kNp;
  int b = idx/(768*kNp);
  int c = k >> 8, py = (k >> 4) & 15, px = k & 15;
  int hp = p >> 4, wp = p & 15;
  pat[idx] = img[(((long)(b*3 + c))*kImg + hp*16 + py)*kImg + wp*16 + px];
}

__global__ void time_freqs(const int* __restrict__ ts, float* __restrict__ temb) {
  int b = blockIdx.x, i = threadIdx.x;              // 128 threads
  float f = expf(-9.210340371976184f * (float)i / 128.f);
  float a = (float)ts[b] * f;
  temb[b*kTdim + i] = cosf(a);
  temb[b*kTdim + 128 + i] = sinf(a);
}

__global__ void silu_kernel(const float* __restrict__ in, float* __restrict__ outp, int n) {
  int i = blockIdx.x*256 + threadIdx.x;
  if (i < n) { float x = in[i]; outp[i] = x / (1.f + expf(-x)); }
}

__device__ __forceinline__ float block_sum(float v) {
  __shared__ float sh[4];
  for (int off = 32; off; off >>= 1) v += __shfl_down(v, off);
  if ((threadIdx.x & 63) == 0) sh[threadIdx.x >> 6] = v;
  __syncthreads();
  float s = sh[0] + sh[1] + sh[2] + sh[3];
  __syncthreads();
  return s;
}

__global__ __launch_bounds__(256) void ln_mod_kernel(
    const float* __restrict__ x, const float* __restrict__ g, const float* __restrict__ be,
    const float* __restrict__ mod, int shOff, int scOff, float* __restrict__ outp) {
  int row = blockIdx.x;                 // b*321 + t
  int b = row / kTok;
  const float* xr = x + (long)row*kDim;
  float s = 0.f, s2 = 0.f;
  for (int i = threadIdx.x; i < kDim; i += 256) { float v = xr[i]; s += v; s2 += v*v; }
  s = block_sum(s); s2 = block_sum(s2);
  float m = s / kDim;
  float inv = rsqrtf(s2 / kDim - m*m + kEps);
  const float* mb = mod + (long)b*(6*kDim);
  for (int i = threadIdx.x; i < kDim; i += 256) {
    float xn = (xr[i] - m)*inv*g[i] + be[i];
    outp[(long)row*kDim + i] = xn*(1.f + mb[scOff + i]) + mb[shOff + i];
  }
}

__global__ __launch_bounds__(256) void final_ln_kernel(
    const float* __restrict__ x, const float* __restrict__ g, const float* __restrict__ be,
    float* __restrict__ yn) {
  int row = blockIdx.x;                 // b*256 + p
  int b = row / kNp, p = row % kNp;
  const float* xr = x + ((long)(b*kTok + kText + 1 + p))*kDim;
  float s = 0.f, s2 = 0.f;
  for (int i = threadIdx.x; i < kDim; i += 256) { float v = xr[i]; s += v; s2 += v*v; }
  s = block_sum(s); s2 = block_sum(s2);
  float m = s / kDim;
  float inv = rsqrtf(s2 / kDim - m*m + kEps);
  for (int i = threadIdx.x; i < kDim; i += 256)
    yn[(long)row*kDim + i] = (xr[i] - m)*inv*g[i] + be[i];
}

// RoPE in-place on q and k (blocks cover whole heads -> barrier makes it race-free)
__global__ __launch_bounds__(256) void rope_kernel(float* __restrict__ q, float* __restrict__ k) {
  int idx = blockIdx.x*256 + threadIdx.x;          // B*321*1024
  int d = idx & (kDim - 1);
  int n = (idx / kDim) % kTok;
  int hd = d & 63;
  int j = hd & 31;
  float inv = expf(-9.210340371976184f * (float)j / 32.f);
  float ang = (float)n * inv;
  float c = cosf(ang), s = sinf(ang);
  int base = idx - hd;
  float qv = q[idx], kv = k[idx];
  float qr, kr;
  if (hd < 32) { qr = -q[base + 2*hd + 1]; kr = -k[base + 2*hd + 1]; }
  else         { qr =  q[base + 2*(hd - 32)]; kr = k[base + 2*(hd - 32)]; }
  __syncthreads();
  q[idx] = qv*c + qr*s;
  k[idx] = kv*c + kr*s;
}

__global__ void softmax_rows(float* __restrict__ sc, int rowLen, int rowStride) {
  long row = blockIdx.x;
  float* r = sc + row*rowStride;
  int t = threadIdx.x;                              // 64 threads = 1 wave
  float mx = -1e30f;
  for (int i = t; i < rowLen; i += 64) mx = fmaxf(mx, r[i]);
  for (int off = 32; off; off >>= 1) mx = fmaxf(mx, __shfl_xor(mx, off));
  float sum = 0.f;
  for (int i = t; i < rowLen; i += 64) { float e = expf(r[i] - mx); r[i] = e; sum += e; }
  for (int off = 32; off; off >>= 1) sum += __shfl_xor(sum, off);
  float invs = 1.f / sum;
  for (int i = t; i < rowLen; i += 64) r[i] *= invs;
}

__global__ void unpatchify(const float* __restrict__ op, float* __restrict__ outp) {
  int idx = blockIdx.x*256 + threadIdx.x;           // B*3*256*256
  int w = idx & 255;
  int h = (idx >> 8) & 255;
  int c = (idx >> 16) % 3;
  int b = idx / (3 * kImg * kImg);
  int hp = h >> 4, py = h & 15, wp = w >> 4, px = w & 15;
  outp[idx] = op[((long)(b*kNp + hp*16 + wp))*768 + c*256 + py*16 + px];
}

// ---------------------------------------------------------------- launch
extern "C" void kernel_launch(void* const* d_in, const int* in_sizes, int n_in,
                              void* d_out, int out_size, void* d_ws, size_t ws_size,
                              hipStream_t stream) {
  (void)in_sizes; (void)n_in; (void)out_size;
  const float* noisy    = (const float*)d_in[0];
  const int*   toks     = (const int*)d_in[1];
  const int*   tsteps   = (const int*)d_in[2];
  const float* W_tok    = (const float*)d_in[3];
  const float* pos_text = (const float*)d_in[4];
  const float* W_patch  = (const float*)d_in[5];
  const float* pos_img  = (const float*)d_in[6];
  const float* cls_tok  = (const float*)d_in[7];
  const float* W_t1     = (const float*)d_in[8];
  const float* b_t1     = (const float*)d_in[9];
  const float* W_t2     = (const float*)d_in[10];
  const float* b_t2     = (const float*)d_in[11];
  const float* ln1_g    = (const float*)d_in[12];
  const float* ln1_b    = (const float*)d_in[13];
  const float* Wq       = (const float*)d_in[14];
  const float* Wk       = (const float*)d_in[15];
  const float* Wv       = (const float*)d_in[16];
  const float* Wo       = (const float*)d_in[17];
  const float* ln2_g    = (const float*)d_in[18];
  const float* ln2_b    = (const float*)d_in[19];
  const float* Wm1      = (const float*)d_in[20];
  const float* Wm2      = (const float*)d_in[21];
  const float* Wada     = (const float*)d_in[22];
  const float* b_ada    = (const float*)d_in[23];
  const float* fn_g     = (const float*)d_in[24];
  const float* fn_b     = (const float*)d_in[25];
  const float* W_final  = (const float*)d_in[26];
  const float* b_final  = (const float*)d_in[27];
  float* out = (float*)d_out;

  float* ws = (float*)d_ws;
  const long seqSz = (long)kBn * kTok * kDim;        // 1,314,816
  float* x    = ws;              ws += seqSz;
  float* xn   = ws;              ws += seqSz;
  float* q    = ws;              ws += seqSz;
  float* k    = ws;              ws += seqSz;
  float* o    = ws;              ws += seqSz;
  float* vt   = ws;              ws += (long)kBn*kHeads*kHd*kScLd;   // V^T [b][h][hd][tok pad]
  float* sc   = ws;              ws += (long)kBn*kHeads*kTok*kScLd;  // scores / MLP hidden
  float* pat  = ws;              ws += (long)kBn*kNp*768;            // also reused as outp
  float* temb = ws;              ws += kBn*kTdim;
  float* t1   = ws;              ws += kBn*kDim;
  float* temb2= ws;              ws += kBn*kDim;
  float* st   = ws;              ws += kBn*kDim;
  float* mod  = ws;              ws += 2L*kBn*6*kDim;
  float* yn   = ws;              ws += (long)kBn*kNp*kDim;
  float* outp = pat;             // patch buffer dead by the time final GEMM runs

  // split-K scratch: 4 splits x max C extent (vt: 4*1024*328 = 1,343,488)
  const long scrStrideVt = (long)kBn*kHeads*kHd*kScLd;   // 1,343,488
  const long scrStrideSq = 1284L*kDim;                   // 1,314,816
  float* scr = ws;               ws += 4*scrStrideVt;
  bool split_ok = ((char*)ws - (char*)d_ws) <= (long)ws_size;

  // --- embeddings
  embed_text_cls<<<(kBn*(kText+1)*kDim)/256, 256, 0, stream>>>(W_tok, toks, pos_text, cls_tok, x);
  extract_patches<<<(kBn*kNp*768)/256, 256, 0, stream>>>(noisy, pat);
  {
    GemmM p = mkm(pat, W_patch, split_ok ? scr : (x + (kText+1)*kDim),
                  kNp, kDim, 768, 768, 768, kDim);
    p.sA0 = (long)kNp*768; p.sC0 = (long)kTok*kDim;
    if (split_ok) {
      p.nSplit = 3; p.splitLen = 256; p.partStride = (long)kBn*kTok*kDim;
      run_mfma_part(stream, false, p, kBn);
      run_reduce(stream, 4, scr, p.partStride, 3, x + (kText+1)*kDim, pos_img,
                 kNp, kDim, kDim, (long)kTok*kDim, 0, 1, kBn, kDim, 1);
    } else {
      p.E = pos_img; p.ldE = kDim;
      run_mfma(stream, 4, false, p, kBn);
    }
  }
  // --- time embedding (skinny GEMV path)
  time_freqs<<<kBn, 128, 0, stream>>>(tsteps, temb);
  gemv4<2><<<kDim/4, 256, 0, stream>>>(temb, W_t1, t1, b_t1, kDim, kTdim, kDim);
  gemv4<1><<<kDim/4, 256, 0, stream>>>(t1, W_t2, temb2, b_t2, kDim, kDim, kDim);
  silu_kernel<<<(kBn*kDim + 255)/256, 256, 0, stream>>>(temb2, st, kBn*kDim);

  for (int l = 0; l < 2; ++l) {
    const float* Wq_l  = Wq  + (long)l*kDim*kDim;
    const float* Wk_l  = Wk  + (long)l*kDim*kDim;
    const float* Wv_l  = Wv  + (long)l*kDim*kDim;
    const float* Wo_l  = Wo  + (long)l*kDim*kDim;
    const float* Wm1_l = Wm1 + (long)l*kMlp*kDim;
    const float* Wm2_l = Wm2 + (long)l*kDim*kMlp;
    float* mod_l = mod + (long)l*kBn*6*kDim;

    gemv4<1><<<(6*kDim)/4, 256, 0, stream>>>(st, Wada + (long)l*6*kDim*kDim, mod_l,
                                             b_ada + (long)l*6*kDim, 6*kDim, kDim, 6*kDim);

    ln_mod_kernel<<<kBn*kTok, 256, 0, stream>>>(x, ln1_g + l*kDim, ln1_b + l*kDim,
                                                mod_l, 0, kDim, xn);
    // Q, K projections (split-K x4)
    for (int qi = 0; qi < 2; ++qi) {
      const float* Wp = qi ? Wk_l : Wq_l;
      float* Cp = qi ? k : q;
      GemmM p = mkm(xn, Wp, split_ok ? scr : Cp, kBn*kTok, kDim, kDim, kDim, kDim, kDim);
      if (split_ok) {
        p.nSplit = 4; p.splitLen = 256; p.partStride = scrStrideSq;
        run_mfma_part(stream, false, p, 1);
        run_reduce(stream, 0, scr, p.partStride, 4, Cp, nullptr,
                   kBn*kTok, kDim, kDim, 0, 0, 1, 1, 0, 1);
      } else run_mfma(stream, 0, false, p, 1);
    }
    { // V projection, transposed output: vt[b][h][hd][tok(pad 328)]
      GemmM p = mkm(xn, Wv_l, split_ok ? scr : vt, kTok, kDim, kDim, kDim, kDim, kScLd);
      p.sA0 = (long)kTok*kDim;
      p.sC0 = (long)kHeads*kHd*kScLd;
      if (split_ok) {
        p.nSplit = 4; p.splitLen = 256; p.partStride = scrStrideVt;
        run_mfma_part(stream, true, p, kBn);
        run_reduce(stream, 0, scr, p.partStride, 4, vt, nullptr,
                   kHeads*kHd, kTok, kScLd, (long)kHeads*kHd*kScLd, 0, 1, kBn, 0, 1);
      } else run_mfma(stream, 0, true, p, kBn);
    }
    rope_kernel<<<(int)(seqSz/256), 256, 0, stream>>>(q, k);

    { // scores = 0.125 * q @ k^T per (b,h), rows padded to 328
      GemmM p = mkm(q, k, sc, kTok, kTok, kHd, kDim, kDim, kScLd);
      p.sA0 = (long)kTok*kDim; p.sA1 = kHd;
      p.sB0 = (long)kTok*kDim; p.sB1 = kHd;
      p.sC0 = (long)kHeads*kTok*kScLd; p.sC1 = (long)kTok*kScLd;
      p.innerB = kHeads; p.alpha = 0.125f;
      run_mfma(stream, 0, false, p, kBn*kHeads);
    }
    softmax_rows<<<kBn*kHeads*kTok, 64, 0, stream>>>(sc, kTok, kScLd);
    { // o = P @ V per (b,h)
      GemmM p = mkm(sc, vt, o, kTok, kHd, kTok, kScLd, kScLd, kDim);
      p.sA0 = (long)kHeads*kTok*kScLd; p.sA1 = (long)kTok*kScLd;
      p.sB0 = (long)kHeads*kHd*kScLd;  p.sB1 = (long)kHd*kScLd;
      p.sC0 = (long)kTok*kDim;         p.sC1 = kHd;
      p.innerB = kHeads;
      run_mfma(stream, 0, false, p, kBn*kHeads);
    }
    { // x += g_msa * (o @ Wo^T)   (split-K x4)
      GemmM p = mkm(o, Wo_l, split_ok ? scr : x, kBn*kTok, kDim, kDim, kDim, kDim, kDim);
      if (split_ok) {
        p.nSplit = 4; p.splitLen = 256; p.partStride = scrStrideSq;
        run_mfma_part(stream, false, p, 1);
        run_reduce(stream, 5, scr, p.partStride, 4, x, mod_l + 2*kDim,
                   kBn*kTok, kDim, kDim, 0, 0, 1, 1, 6*kDim, kTok);
      } else {
        p.E = mod_l + 2*kDim; p.ldE = 6*kDim; p.rowsPB = kTok;
        run_mfma(stream, 5, false, p, 1);
      }
    }
    ln_mod_kernel<<<kBn*kTok, 256, 0, stream>>>(x, ln2_g + l*kDim, ln2_b + l*kDim,
                                                mod_l, 3*kDim, 4*kDim, xn);
    { // MLP1 (grid already large: no split)
      GemmM p = mkm(xn, Wm1_l, sc, kBn*kTok, kMlp, kDim, kDim, kDim, kMlp);
      run_mfma(stream, 3, false, p, 1);
    }
    { // MLP2 (split-K x4, K=4096)
      GemmM p = mkm(sc, Wm2_l, split_ok ? scr : x, kBn*kTok, kDim, kMlp, kMlp, kMlp, kDim);
      if (split_ok) {
        p.nSplit = 4; p.splitLen = 1024; p.partStride = scrStrideSq;
        run_mfma_part(stream, false, p, 1);
        run_reduce(stream, 5, scr, p.partStride, 4, x, mod_l + 5*kDim,
                   kBn*kTok, kDim, kDim, 0, 0, 1, 1, 6*kDim, kTok);
      } else {
        p.E = mod_l + 5*kDim; p.ldE = 6*kDim; p.rowsPB = kTok;
        run_mfma(stream, 5, false, p, 1);
      }
    }
  }

  final_ln_kernel<<<kBn*kNp, 256, 0, stream>>>(x, fn_g, fn_b, yn);
  { // final projection (split-K x4)
    GemmM p = mkm(yn, W_final, split_ok ? scr : outp, kBn*kNp, 768, kDim, kDim, kDim, 768);
    if (split_ok) {
      p.nSplit = 4; p.splitLen = 256; p.partStride = (long)kBn*kNp*768;
      run_mfma_part(stream, false, p, 1);
      run_reduce(stream, 1, scr, p.partStride, 4, outp, b_final,
                 kBn*kNp, 768, 768, 0, 0, 1, 1, 0, 1);
    } else {
      p.E = b_final;
      run_mfma(stream, 1, false, p, 1);
    }
  }
  unpatchify<<<(kBn*3*kImg*kImg)/256, 256, 0, stream>>>(outp, out);
}